// Round 3
// baseline (302.709 us; speedup 1.0000x reference)
//
#include <hip/hip_runtime.h>
#include <hip/hip_bf16.h>

// GraphSAGE 2-layer forward.
// R17 = R16 + two latency fixes identified by post-mortem:
//  FIX A (finalize): the 196 finalize blocks were the true ~60us pole of
//    gemm128_csr (not the GEMM: occupancy 18->43% changed nothing). The
//    per-thread 32-run serial chain (LDS meta -> global load -> LDS atomic,
//    ~700cy each, x2 passes) is replaced by flat-index iteration over the
//    bucket's concatenated segment with a 9-step LDS binary search per
//    element (runbase[513] scan reinstated). All global loads/atomics are
//    now independent; unrolled x4 for explicit MLP.
//  FIX B (gathers): R16 proved gather_h is latency-bound on the gather loads
//    themselves (shfl removal + sort were neutral; FETCH at compulsory
//    floor). Double MLP: each 4-lane group owns TWO degree-sorted-adjacent
//    nodes (block = 128 nodes) -> 16 independent gathers in flight/iter.
//    Beyond-degree iterations redirect branchlessly to the sentinel zero
//    row (cndmask to index N).

#define THREADS 256
#define NBLK1 512          // csr part1 blocks (chunk = 3125 <= 3328 stage cap)
#define CSTRIDE 12288      // padded csr entries per 256-node bucket

typedef __bf16 bf16x8 __attribute__((ext_vector_type(8)));
typedef float floatx4 __attribute__((ext_vector_type(4)));
typedef float f32x4 __attribute__((ext_vector_type(4)));
typedef unsigned int u32x4 __attribute__((ext_vector_type(4)));

union ABfrag { bf16x8 v; unsigned short u[8]; uint4 q; };
union V4 { u32x4 w; uint4 q; };

static __device__ __forceinline__ unsigned short f2bf(float f) {
    unsigned int u = __float_as_uint(f);
    u = (u + 0x7fffu + ((u >> 16) & 1u)) >> 16;   // RNE
    return (unsigned short)u;
}

static __device__ __forceinline__ void unpack8(float* o, uint4 v) {
    o[0] = __uint_as_float(v.x << 16);
    o[1] = __uint_as_float(v.x & 0xffff0000u);
    o[2] = __uint_as_float(v.y << 16);
    o[3] = __uint_as_float(v.y & 0xffff0000u);
    o[4] = __uint_as_float(v.z << 16);
    o[5] = __uint_as_float(v.z & 0xffff0000u);
    o[6] = __uint_as_float(v.w << 16);
    o[7] = __uint_as_float(v.w & 0xffff0000u);
}

static __device__ __forceinline__ void acc8(float* acc, uint4 v) {
    float t[8];
    unpack8(t, v);
    #pragma unroll
    for (int i = 0; i < 8; ++i) acc[i] += t[i];
}

// 8 gathers from one packed csr vector (indices s0..s7), accumulate.
static __device__ __forceinline__ void gath8(float* acc, const unsigned short* __restrict__ ps,
                                             u32x4 c, int lane) {
    unsigned s0 = c[0] & 0xffffu, s1 = c[0] >> 16;
    unsigned s2 = c[1] & 0xffffu, s3 = c[1] >> 16;
    unsigned s4 = c[2] & 0xffffu, s5 = c[2] >> 16;
    unsigned s6 = c[3] & 0xffffu, s7 = c[3] >> 16;
    acc8(acc, *(const uint4*)&ps[(size_t)s0 * 32 + lane * 8]);
    acc8(acc, *(const uint4*)&ps[(size_t)s1 * 32 + lane * 8]);
    acc8(acc, *(const uint4*)&ps[(size_t)s2 * 32 + lane * 8]);
    acc8(acc, *(const uint4*)&ps[(size_t)s3 * 32 + lane * 8]);
    acc8(acc, *(const uint4*)&ps[(size_t)s4 * 32 + lane * 8]);
    acc8(acc, *(const uint4*)&ps[(size_t)s5 * 32 + lane * 8]);
    acc8(acc, *(const uint4*)&ps[(size_t)s6 * 32 + lane * 8]);
    acc8(acc, *(const uint4*)&ps[(size_t)s7 * 32 + lane * 8]);
}

// ---------------------------------------------------------------------------
// D1: fused cast (x->bf16, W->bf16) + CSR part1 + zero-row init for p1/p2.
__global__ __launch_bounds__(THREADS)
void fused_cast_p1(const float* __restrict__ x, const float* __restrict__ wa,
                   const float* __restrict__ wb, const float* __restrict__ wc,
                   const float* __restrict__ wd, unsigned short* __restrict__ xb,
                   unsigned short* __restrict__ Wb, int nx4,
                   const int* __restrict__ src, const int* __restrict__ dst,
                   unsigned int* __restrict__ pairs, unsigned int* __restrict__ counts,
                   int E, int chunk, int NB,
                   unsigned short* __restrict__ p1z, unsigned short* __restrict__ p2z, int Nn) {
    __shared__ int lh[THREADS], lsc[THREADS], lpos[THREADS];
    __shared__ unsigned int stage[3328];
    int t = threadIdx.x;
    if (blockIdx.x < NBLK1) {
        int e0 = blockIdx.x * chunk, e1 = min(E, e0 + chunk);
        lh[t] = 0;
        __syncthreads();
        for (int e = e0 + t; e < e1; e += THREADS) atomicAdd(&lh[dst[e] >> 8], 1);
        __syncthreads();
        int v = lh[t];
        lsc[t] = v;
        __syncthreads();
        for (int off = 1; off < THREADS; off <<= 1) {
            int tv = (t >= off) ? lsc[t - off] : 0;
            __syncthreads();
            lsc[t] += tv;
            __syncthreads();
        }
        int base = lsc[t] - v;
        lpos[t] = base;
        __syncthreads();
        for (int e = e0 + t; e < e1; e += THREADS) {
            int dd = dst[e];
            int p = atomicAdd(&lpos[dd >> 8], 1);
            stage[p] = (unsigned int)src[e] | ((unsigned int)(dd & 255) << 16);
        }
        __syncthreads();
        int n = e1 - e0;
        for (int i = t; i < n; i += THREADS) pairs[e0 + i] = stage[i];
        if (t < NB)
            counts[(size_t)blockIdx.x * 256 + t] = ((unsigned int)base << 16) | (unsigned int)v;
        return;
    }
    // zero-row init: p1 has 4 slabs of stride (N+1)*32, p2 has 2
    if (blockIdx.x == NBLK1 && t < 192) {
        int wi = t & 31;
        size_t Np32 = (size_t)(Nn + 1) * 32;
        if (t < 128) p1z[(size_t)(t >> 5) * Np32 + (size_t)Nn * 32 + wi] = 0;
        else         p2z[(size_t)((t - 128) >> 5) * Np32 + (size_t)Nn * 32 + wi] = 0;
    }
    int i = (blockIdx.x - NBLK1) * THREADS + t;
    if (i < nx4) {
        float4 v = ((const float4*)x)[i];
        ushort4 u;
        u.x = f2bf(v.x); u.y = f2bf(v.y); u.z = f2bf(v.z); u.w = f2bf(v.w);
        ((ushort4*)xb)[i] = u;
        return;
    }
    int j = i - nx4;
    if (j >= 49152) return;
    float v;
    if (j < 16384) v = wa[j];
    else if (j < 32768) v = wb[j - 16384];
    else if (j < 40960) v = wc[j - 32768];
    else v = wd[j - 40960];
    Wb[j] = f2bf(v);
}

// ---------------------------------------------------------------------------
// MFMA bf16 GEMM body (R9-proven). pOut tables (gathered later) are padded:
// slab stride (M+1)*32 with row M = zeros. rOut tables unpadded (M*32).
template<int NOUT, bool ASLAB>
static __device__ __forceinline__
void gemm_body(const unsigned short* __restrict__ A, const unsigned short* __restrict__ W0,
               const unsigned short* __restrict__ W1, const float* __restrict__ biasR,
               unsigned short* __restrict__ pOut, unsigned short* __restrict__ rOut,
               int M, int job, int xt) {
    constexpr int CT = 4;
    int outSel, chalf;
    if (NOUT == 128) { outSel = job >> 1; chalf = job & 1; }
    else             { outSel = job;      chalf = 0; }
    const unsigned short* W = (outSel ? W1 : W0) + chalf * 64 * 128;

    const int wv = threadIdx.x >> 6, ln = threadIdx.x & 63;
    const int bl = ln & 15, quad = ln >> 4;
    const int mt = xt * 4 + wv;
    const size_t M32 = (size_t)M * 32;
    const size_t Mp32 = (size_t)(M + 1) * 32;

    ABfrag Bf[CT][4];
    #pragma unroll
    for (int ct = 0; ct < CT; ++ct)
        #pragma unroll
        for (int ks = 0; ks < 4; ++ks)
            Bf[ct][ks].q = *(const uint4*)&W[(size_t)(ct * 16 + bl) * 128 + ks * 32 + quad * 8];

    if (mt * 16 >= M) return;
    const int m0 = mt * 16;
    const int arow = m0 + bl;

    floatx4 acc[CT];
    #pragma unroll
    for (int ct = 0; ct < CT; ++ct) acc[ct] = (floatx4){0.f, 0.f, 0.f, 0.f};

    #pragma unroll
    for (int ks = 0; ks < 4; ++ks) {
        ABfrag Af;
        if (ASLAB) Af.q = *(const uint4*)&A[(size_t)ks * M32 + (size_t)arow * 32 + quad * 8];
        else       Af.q = *(const uint4*)&A[(size_t)arow * 128 + ks * 32 + quad * 8];
        #pragma unroll
        for (int ct = 0; ct < CT; ++ct)
            acc[ct] = __builtin_amdgcn_mfma_f32_16x16x32_bf16(Af.v, Bf[ct][ks].v, acc[ct], 0, 0, 0);
    }

    unsigned short* outp = outSel ? rOut : pOut;
    const size_t ostride = outSel ? M32 : Mp32;
    #pragma unroll
    for (int ct = 0; ct < CT; ++ct) {
        int col = chalf * 64 + ct * 16 + bl;
        int slab = col >> 5, wi = col & 31;
        size_t sbase = (size_t)slab * ostride;
        float bv = outSel ? biasR[col] : 0.f;
        #pragma unroll
        for (int i = 0; i < 4; ++i) {
            int row = m0 + quad * 4 + i;
            outp[sbase + (size_t)row * 32 + wi] = f2bf(acc[ct][i] + bv);
        }
    }
}

// ---------------------------------------------------------------------------
// D2: fused layer-1 GEMM + flat-index CSR finalize.
// grid (gemmBlocks, 5): y>=1 -> gemm job y-1; y==0 && x<NB -> finalize.
__global__ __launch_bounds__(THREADS)
void gemm128_csr(const unsigned short* __restrict__ A, const unsigned short* __restrict__ W0,
                 const unsigned short* __restrict__ W1, const float* __restrict__ biasR,
                 unsigned short* __restrict__ pOut, unsigned short* __restrict__ rOut, int M,
                 const unsigned int* __restrict__ pairs, const unsigned int* __restrict__ counts,
                 int* __restrict__ rowptr, unsigned short* __restrict__ degs,
                 unsigned short* __restrict__ csr, int N, int E, int NB, int chunk) {
    __shared__ int runsrc[NBLK1];
    __shared__ int runbase[NBLK1 + 1];
    __shared__ int lhist[THREADS], lscan[THREADS], loff[THREADS];

    if (blockIdx.y != 0) {
        gemm_body<128, false>(A, W0, W1, biasR, pOut, rOut, M, blockIdx.y - 1, blockIdx.x);
        return;
    }
    int b = blockIdx.x, t = threadIdx.x;
    if (b >= NB) return;

    // per-run {length, source offset} from counts; scan lengths -> runbase
    unsigned int pc0 = counts[(size_t)t * 256 + b];
    unsigned int pc1 = counts[(size_t)(t + 256) * 256 + b];
    int c0 = (int)(pc0 & 0xffffu), c1 = (int)(pc1 & 0xffffu);
    runsrc[t] = t * chunk + (int)(pc0 >> 16);
    runsrc[t + 256] = (t + 256) * chunk + (int)(pc1 >> 16);
    lscan[t] = c0;
    __syncthreads();
    for (int off = 1; off < THREADS; off <<= 1) {
        int xx = (t >= off) ? lscan[t - off] : 0;
        __syncthreads();
        lscan[t] += xx;
        __syncthreads();
    }
    runbase[t] = lscan[t] - c0;
    int S0 = lscan[THREADS - 1];
    __syncthreads();
    lscan[t] = c1;
    __syncthreads();
    for (int off = 1; off < THREADS; off <<= 1) {
        int xx = (t >= off) ? lscan[t - off] : 0;
        __syncthreads();
        lscan[t] += xx;
        __syncthreads();
    }
    runbase[256 + t] = S0 + lscan[t] - c1;
    if (t == THREADS - 1) runbase[512] = S0 + lscan[t];
    lhist[t] = 0;
    __syncthreads();
    int sz = runbase[512];

    // Pass A: flat-index histogram. Each element independent: 9-step LDS
    // binary search for its run, then one global load + one LDS atomic.
    // Unrolled x4 so 4 loads are in flight per thread.
    for (int i0 = t; i0 < sz; i0 += 4 * THREADS) {
        unsigned pv[4];
        int ok[4];
        #pragma unroll
        for (int k = 0; k < 4; ++k) {
            int i = i0 + k * THREADS;
            ok[k] = (i < sz);
            int idx = ok[k] ? i : (sz - 1);
            int lo = 0, hi = NBLK1;
            #pragma unroll
            for (int s = 0; s < 9; ++s) {
                int mid = (lo + hi) >> 1;
                bool c = runbase[mid] <= idx;
                lo = c ? mid : lo;
                hi = c ? hi : mid;
            }
            pv[k] = pairs[runsrc[lo] + (idx - runbase[lo])];
        }
        #pragma unroll
        for (int k = 0; k < 4; ++k)
            if (ok[k]) atomicAdd(&lhist[(pv[k] >> 16) & 255], 1);
    }
    __syncthreads();

    // padded (8-aligned) counts -> scan -> rowptr / degs / loff / sentinel pads
    int v = lhist[t];
    int pcv = (v + 7) & ~7;
    lscan[t] = pcv;
    __syncthreads();
    for (int off = 1; off < THREADS; off <<= 1) {
        int xx = (t >= off) ? lscan[t - off] : 0;
        __syncthreads();
        lscan[t] += xx;
        __syncthreads();
    }
    int rel = lscan[t] - pcv;
    int base = b * CSTRIDE + rel;
    int id = (b << 8) + t;
    if (id < N) {
        rowptr[id] = base;
        degs[id] = (unsigned short)v;
    }
    loff[t] = base;
    for (int i = v; i < pcv; ++i) csr[base + i] = (unsigned short)N;  // sentinel -> zero row
    __syncthreads();

    // Pass B: flat-index scatter (pairs L2-warm from pass A).
    for (int i0 = t; i0 < sz; i0 += 4 * THREADS) {
        unsigned pv[4];
        int ok[4];
        #pragma unroll
        for (int k = 0; k < 4; ++k) {
            int i = i0 + k * THREADS;
            ok[k] = (i < sz);
            int idx = ok[k] ? i : (sz - 1);
            int lo = 0, hi = NBLK1;
            #pragma unroll
            for (int s = 0; s < 9; ++s) {
                int mid = (lo + hi) >> 1;
                bool c = runbase[mid] <= idx;
                lo = c ? mid : lo;
                hi = c ? hi : mid;
            }
            pv[k] = pairs[runsrc[lo] + (idx - runbase[lo])];
        }
        #pragma unroll
        for (int k = 0; k < 4; ++k)
            if (ok[k]) {
                int pos = atomicAdd(&loff[(pv[k] >> 16) & 255], 1);
                csr[pos] = (unsigned short)(pv[k] & 0xffffu);
            }
    }
}

// D4: layer-2 GEMM (A = h bf16 slab-major unpadded, p2 out padded).
__global__ __launch_bounds__(THREADS)
void gemm64(const unsigned short* __restrict__ A, const unsigned short* __restrict__ W0,
            const unsigned short* __restrict__ W1, const float* __restrict__ b2,
            unsigned short* __restrict__ p2, unsigned short* __restrict__ r2, int M) {
    gemm_body<64, true>(A, W0, W1, b2, p2, r2, M, blockIdx.y, blockIdx.x);
}

// ---------------------------------------------------------------------------
// D3: gather layer 1. Block = 128 nodes; each 4-lane group owns TWO
// degree-sorted-adjacent nodes -> 16 independent gathers in flight per iter.
__global__ __launch_bounds__(THREADS)
void gather_h(const unsigned short* __restrict__ p1, const int* __restrict__ rowptr,
              const unsigned short* __restrict__ degs, const unsigned short* __restrict__ csr,
              const unsigned short* __restrict__ r1, unsigned short* __restrict__ h,
              int N, int nodeBlocks) {
    __shared__ int sdeg[128], perm[128];
    const size_t N32 = (size_t)N * 32;
    const size_t Np32 = (size_t)(N + 1) * 32;
    int slab = blockIdx.x / nodeBlocks;
    int nb = blockIdx.x - slab * nodeBlocks;
    int g0 = nb * 128;
    int t = threadIdx.x;
    if (t < 128) {
        int g = g0 + t;
        sdeg[t] = (g < N) ? (int)degs[g] : -1;
    }
    __syncthreads();
    if (t < 128) {
        int d = sdeg[t], r = 0;
        #pragma unroll 8
        for (int j = 0; j < 128; ++j) {
            int dj = sdeg[j];
            r += (dj < d) || (dj == d && j < t);
        }
        perm[r] = t;
    }
    __syncthreads();
    int grp = t >> 2, lane = t & 3;
    int la = perm[2 * grp], lb = perm[2 * grp + 1];
    int ga = g0 + la, gb = g0 + lb;
    int da = sdeg[la], db = sdeg[lb];
    const unsigned short* ps = p1 + (size_t)slab * Np32;
    int sa = rowptr[min(ga, N - 1)];
    int sb = rowptr[min(gb, N - 1)];
    int na = (da + 7) >> 3, nb2 = (db + 7) >> 3;   // da=-1 -> 0
    int nmax = max(na, nb2);
    const unsigned short* cpa = csr + sa;
    const unsigned short* cpb = csr + sb;
    unsigned SENT2 = ((unsigned)N << 16) | (unsigned)N;
    u32x4 sentv = {SENT2, SENT2, SENT2, SENT2};
    float accA[8] = {0.f, 0.f, 0.f, 0.f, 0.f, 0.f, 0.f, 0.f};
    float accB[8] = {0.f, 0.f, 0.f, 0.f, 0.f, 0.f, 0.f, 0.f};
    for (int it = 0; it < nmax; ++it) {
        u32x4 ca = __builtin_nontemporal_load((const u32x4*)(cpa + min(it, na - 1) * 8));
        u32x4 cb = __builtin_nontemporal_load((const u32x4*)(cpb + min(it, nb2 - 1) * 8));
        if (it >= na) ca = sentv;
        if (it >= nb2) cb = sentv;
        gath8(accA, ps, ca, lane);
        gath8(accB, ps, cb, lane);
    }
    float rca = 1.0f / fmaxf((float)da, 1.0f);
    float rcb = 1.0f / fmaxf((float)db, 1.0f);
    V4 rva, rvb;
    rva.w = __builtin_nontemporal_load((const u32x4*)(r1 + slab * N32 + (size_t)min(ga, N - 1) * 32 + lane * 8));
    rvb.w = __builtin_nontemporal_load((const u32x4*)(r1 + slab * N32 + (size_t)min(gb, N - 1) * 32 + lane * 8));
    float rra[8], rrb[8];
    unpack8(rra, rva.q);
    unpack8(rrb, rvb.q);
    if (ga < N) {
        float o[8];
        #pragma unroll
        for (int i = 0; i < 8; ++i) o[i] = fmaxf(accA[i] * rca + rra[i], 0.f);
        u32x4 u;
        u[0] = (unsigned)f2bf(o[0]) | ((unsigned)f2bf(o[1]) << 16);
        u[1] = (unsigned)f2bf(o[2]) | ((unsigned)f2bf(o[3]) << 16);
        u[2] = (unsigned)f2bf(o[4]) | ((unsigned)f2bf(o[5]) << 16);
        u[3] = (unsigned)f2bf(o[6]) | ((unsigned)f2bf(o[7]) << 16);
        __builtin_nontemporal_store(u, (u32x4*)(h + slab * N32 + (size_t)ga * 32 + lane * 8));
    }
    if (gb < N) {
        float o[8];
        #pragma unroll
        for (int i = 0; i < 8; ++i) o[i] = fmaxf(accB[i] * rcb + rrb[i], 0.f);
        u32x4 u;
        u[0] = (unsigned)f2bf(o[0]) | ((unsigned)f2bf(o[1]) << 16);
        u[1] = (unsigned)f2bf(o[2]) | ((unsigned)f2bf(o[3]) << 16);
        u[2] = (unsigned)f2bf(o[4]) | ((unsigned)f2bf(o[5]) << 16);
        u[3] = (unsigned)f2bf(o[6]) | ((unsigned)f2bf(o[7]) << 16);
        __builtin_nontemporal_store(u, (u32x4*)(h + slab * N32 + (size_t)gb * 32 + lane * 8));
    }
}

// D5: gather layer 2 (final): out[g][s*32+d] = mean p2[s][src][d] + r2[s][g][d]
__global__ __launch_bounds__(THREADS)
void gather_out(const unsigned short* __restrict__ p2, const int* __restrict__ rowptr,
                const unsigned short* __restrict__ degs, const unsigned short* __restrict__ csr,
                const unsigned short* __restrict__ r2, float* __restrict__ out,
                int N, int nodeBlocks) {
    __shared__ int sdeg[128], perm[128];
    const size_t N32 = (size_t)N * 32;
    const size_t Np32 = (size_t)(N + 1) * 32;
    int slab = blockIdx.x / nodeBlocks;
    int nb = blockIdx.x - slab * nodeBlocks;
    int g0 = nb * 128;
    int t = threadIdx.x;
    if (t < 128) {
        int g = g0 + t;
        sdeg[t] = (g < N) ? (int)degs[g] : -1;
    }
    __syncthreads();
    if (t < 128) {
        int d = sdeg[t], r = 0;
        #pragma unroll 8
        for (int j = 0; j < 128; ++j) {
            int dj = sdeg[j];
            r += (dj < d) || (dj == d && j < t);
        }
        perm[r] = t;
    }
    __syncthreads();
    int grp = t >> 2, lane = t & 3;
    int la = perm[2 * grp], lb = perm[2 * grp + 1];
    int ga = g0 + la, gb = g0 + lb;
    int da = sdeg[la], db = sdeg[lb];
    const unsigned short* ps = p2 + (size_t)slab * Np32;
    int sa = rowptr[min(ga, N - 1)];
    int sb = rowptr[min(gb, N - 1)];
    int na = (da + 7) >> 3, nb2 = (db + 7) >> 3;
    int nmax = max(na, nb2);
    const unsigned short* cpa = csr + sa;
    const unsigned short* cpb = csr + sb;
    unsigned SENT2 = ((unsigned)N << 16) | (unsigned)N;
    u32x4 sentv = {SENT2, SENT2, SENT2, SENT2};
    float accA[8] = {0.f, 0.f, 0.f, 0.f, 0.f, 0.f, 0.f, 0.f};
    float accB[8] = {0.f, 0.f, 0.f, 0.f, 0.f, 0.f, 0.f, 0.f};
    for (int it = 0; it < nmax; ++it) {
        u32x4 ca = __builtin_nontemporal_load((const u32x4*)(cpa + min(it, na - 1) * 8));
        u32x4 cb = __builtin_nontemporal_load((const u32x4*)(cpb + min(it, nb2 - 1) * 8));
        if (it >= na) ca = sentv;
        if (it >= nb2) cb = sentv;
        gath8(accA, ps, ca, lane);
        gath8(accB, ps, cb, lane);
    }
    float rca = 1.0f / fmaxf((float)da, 1.0f);
    float rcb = 1.0f / fmaxf((float)db, 1.0f);
    V4 rva, rvb;
    rva.w = __builtin_nontemporal_load((const u32x4*)(r2 + slab * N32 + (size_t)min(ga, N - 1) * 32 + lane * 8));
    rvb.w = __builtin_nontemporal_load((const u32x4*)(r2 + slab * N32 + (size_t)min(gb, N - 1) * 32 + lane * 8));
    float rra[8], rrb[8];
    unpack8(rra, rva.q);
    unpack8(rrb, rvb.q);
    if (ga < N) {
        f32x4 o0, o1;
        #pragma unroll
        for (int i = 0; i < 4; ++i) o0[i] = accA[i] * rca + rra[i];
        #pragma unroll
        for (int i = 0; i < 4; ++i) o1[i] = accA[4 + i] * rca + rra[4 + i];
        f32x4* o4 = (f32x4*)(out + (size_t)ga * 64 + slab * 32 + lane * 8);
        __builtin_nontemporal_store(o0, o4);
        __builtin_nontemporal_store(o1, o4 + 1);
    }
    if (gb < N) {
        f32x4 o0, o1;
        #pragma unroll
        for (int i = 0; i < 4; ++i) o0[i] = accB[i] * rcb + rrb[i];
        #pragma unroll
        for (int i = 0; i < 4; ++i) o1[i] = accB[4 + i] * rcb + rrb[4 + i];
        f32x4* o4 = (f32x4*)(out + (size_t)gb * 64 + slab * 32 + lane * 8);
        __builtin_nontemporal_store(o0, o4);
        __builtin_nontemporal_store(o1, o4 + 1);
    }
}

// ---------------------------------------------------------------------------
extern "C" void kernel_launch(void* const* d_in, const int* in_sizes, int n_in,
                              void* d_out, int out_size, void* d_ws, size_t ws_size,
                              hipStream_t stream) {
    const float* x   = (const float*)d_in[0];
    const int* edges = (const int*)d_in[1];
    const float* Wl1 = (const float*)d_in[2];
    const float* Wr1 = (const float*)d_in[3];
    const float* b1  = (const float*)d_in[4];
    const float* Wl2 = (const float*)d_in[5];
    const float* Wr2 = (const float*)d_in[6];
    const float* b2  = (const float*)d_in[7];
    float* out = (float*)d_out;

    const int N = in_sizes[0] / 128;     // 50000 (< 65536)
    const int E = in_sizes[1] / 2;       // 1600000
    const int NB = (N + 255) >> 8;       // 196
    const int chunk = (E + NBLK1 - 1) / NBLK1;   // 3125
    const int* src = edges;
    const int* dstv = edges + E;

    // Workspace (slab-major tables; p1/p2 padded with zero row N)
    char* wsp = (char*)d_ws;
    unsigned short* p1  = (unsigned short*)wsp;  wsp += (size_t)(N + 1) * 128 * 2;
    unsigned short* r1  = (unsigned short*)wsp;  wsp += (size_t)N * 128 * 2;
    unsigned short* h   = (unsigned short*)wsp;  wsp += (size_t)N * 128 * 2;
    unsigned short* p2  = (unsigned short*)wsp;  wsp += (size_t)(N + 1) * 64 * 2;
    unsigned short* r2  = (unsigned short*)wsp;  wsp += (size_t)N * 64 * 2;
    unsigned short* xb  = (unsigned short*)wsp;  wsp += (size_t)N * 128 * 2;
    unsigned int* pairs = (unsigned int*)wsp;    wsp += (size_t)E * 4;
    unsigned short* csr = (unsigned short*)wsp;  wsp += (size_t)NB * CSTRIDE * 2;  // 4.8 MB
    unsigned short* Wb  = (unsigned short*)wsp;  wsp += (size_t)49152 * 2;
    unsigned int* counts= (unsigned int*)wsp;    wsp += (size_t)NBLK1 * 256 * 4;
    int* rowptr         = (int*)wsp;             wsp += (size_t)(N + 1) * 4;
    unsigned short* degs= (unsigned short*)wsp;  wsp += (size_t)((N + 1) & ~1) * 2;

    unsigned short* Wl1b = Wb;
    unsigned short* Wr1b = Wb + 16384;
    unsigned short* Wl2b = Wb + 32768;
    unsigned short* Wr2b = Wb + 40960;

    const int nx4 = N * 128 / 4;
    const int castBlocks = (nx4 + 49152 + THREADS - 1) / THREADS;
    const int MT = (N + 15) / 16;                 // 3125
    const int gemmBlocks = (MT + 3) / 4;          // 782
    const int nodeBlocks = (N + 127) / 128;       // 391

    // D1: fused cast + CSR part1 + zero-row init
    fused_cast_p1<<<NBLK1 + castBlocks, THREADS, 0, stream>>>(
        x, Wl1, Wr1, Wl2, Wr2, xb, Wb, nx4, src, dstv, pairs, counts, E, chunk, NB,
        p1, p2, N);

    // D2: layer-1 GEMM (4 jobs) + flat-index CSR finalize (y==0)
    gemm128_csr<<<dim3(gemmBlocks, 5), THREADS, 0, stream>>>(
        xb, Wl1b, Wr1b, b1, p1, r1, N,
        pairs, counts, rowptr, degs, csr, N, E, NB, chunk);

    // D3: gather layer 1 (4 slabs)
    gather_h<<<4 * nodeBlocks, THREADS, 0, stream>>>(p1, rowptr, degs, csr, r1, h, N, nodeBlocks);

    // D4: layer-2 GEMM
    gemm64<<<dim3(gemmBlocks, 2), THREADS, 0, stream>>>(h, Wl2b, Wr2b, b2, p2, r2, N);

    // D5: gather layer 2 -> final output
    gather_out<<<2 * nodeBlocks, THREADS, 0, stream>>>(p2, rowptr, degs, csr, r2, out, N, nodeBlocks);
}

// Round 4
// 275.186 us; speedup vs baseline: 1.1000x; 1.1000x over previous
//
#include <hip/hip_runtime.h>
#include <hip/hip_bf16.h>

// GraphSAGE 2-layer forward.
// R18 = R17 + XCD-pinned slab mapping for the gathers.
// Post-mortem R17: 2-node MLP raised gather throughput (2.33->2.82 TB/s) but
// FETCH jumped +102MB = exactly one extra p1 replication: grid shrank to
// 1564 blocks = fully resident, so every XCD ran all 4 slabs concurrently
// (12.8MB hot in 4MB L2 -> thrash). Fix: blockIdx%8 = XCD (round-robin
// dispatch idiom); pin slab s of gather_h to XCD pair s, slab s of
// gather_out to XCD quad s. Per-XCD L2 working set = one 3.2MB slab.
// p1 gather fetch 204.8 -> 25.6MB; p2 51 -> 25.6MB. Bijective (slab,nb)
// cover, so wrong-XCD-mapping only costs speed, never correctness.

#define THREADS 256
#define NBLK1 512          // csr part1 blocks (chunk = 3125 <= 3328 stage cap)
#define CSTRIDE 12288      // padded csr entries per 256-node bucket

typedef __bf16 bf16x8 __attribute__((ext_vector_type(8)));
typedef float floatx4 __attribute__((ext_vector_type(4)));
typedef float f32x4 __attribute__((ext_vector_type(4)));
typedef unsigned int u32x4 __attribute__((ext_vector_type(4)));

union ABfrag { bf16x8 v; unsigned short u[8]; uint4 q; };
union V4 { u32x4 w; uint4 q; };

static __device__ __forceinline__ unsigned short f2bf(float f) {
    unsigned int u = __float_as_uint(f);
    u = (u + 0x7fffu + ((u >> 16) & 1u)) >> 16;   // RNE
    return (unsigned short)u;
}

static __device__ __forceinline__ void unpack8(float* o, uint4 v) {
    o[0] = __uint_as_float(v.x << 16);
    o[1] = __uint_as_float(v.x & 0xffff0000u);
    o[2] = __uint_as_float(v.y << 16);
    o[3] = __uint_as_float(v.y & 0xffff0000u);
    o[4] = __uint_as_float(v.z << 16);
    o[5] = __uint_as_float(v.z & 0xffff0000u);
    o[6] = __uint_as_float(v.w << 16);
    o[7] = __uint_as_float(v.w & 0xffff0000u);
}

static __device__ __forceinline__ void acc8(float* acc, uint4 v) {
    float t[8];
    unpack8(t, v);
    #pragma unroll
    for (int i = 0; i < 8; ++i) acc[i] += t[i];
}

// 8 gathers from one packed csr vector (indices s0..s7), accumulate.
static __device__ __forceinline__ void gath8(float* acc, const unsigned short* __restrict__ ps,
                                             u32x4 c, int lane) {
    unsigned s0 = c[0] & 0xffffu, s1 = c[0] >> 16;
    unsigned s2 = c[1] & 0xffffu, s3 = c[1] >> 16;
    unsigned s4 = c[2] & 0xffffu, s5 = c[2] >> 16;
    unsigned s6 = c[3] & 0xffffu, s7 = c[3] >> 16;
    acc8(acc, *(const uint4*)&ps[(size_t)s0 * 32 + lane * 8]);
    acc8(acc, *(const uint4*)&ps[(size_t)s1 * 32 + lane * 8]);
    acc8(acc, *(const uint4*)&ps[(size_t)s2 * 32 + lane * 8]);
    acc8(acc, *(const uint4*)&ps[(size_t)s3 * 32 + lane * 8]);
    acc8(acc, *(const uint4*)&ps[(size_t)s4 * 32 + lane * 8]);
    acc8(acc, *(const uint4*)&ps[(size_t)s5 * 32 + lane * 8]);
    acc8(acc, *(const uint4*)&ps[(size_t)s6 * 32 + lane * 8]);
    acc8(acc, *(const uint4*)&ps[(size_t)s7 * 32 + lane * 8]);
}

// ---------------------------------------------------------------------------
// D1: fused cast (x->bf16, W->bf16) + CSR part1 + zero-row init for p1/p2.
__global__ __launch_bounds__(THREADS)
void fused_cast_p1(const float* __restrict__ x, const float* __restrict__ wa,
                   const float* __restrict__ wb, const float* __restrict__ wc,
                   const float* __restrict__ wd, unsigned short* __restrict__ xb,
                   unsigned short* __restrict__ Wb, int nx4,
                   const int* __restrict__ src, const int* __restrict__ dst,
                   unsigned int* __restrict__ pairs, unsigned int* __restrict__ counts,
                   int E, int chunk, int NB,
                   unsigned short* __restrict__ p1z, unsigned short* __restrict__ p2z, int Nn) {
    __shared__ int lh[THREADS], lsc[THREADS], lpos[THREADS];
    __shared__ unsigned int stage[3328];
    int t = threadIdx.x;
    if (blockIdx.x < NBLK1) {
        int e0 = blockIdx.x * chunk, e1 = min(E, e0 + chunk);
        lh[t] = 0;
        __syncthreads();
        for (int e = e0 + t; e < e1; e += THREADS) atomicAdd(&lh[dst[e] >> 8], 1);
        __syncthreads();
        int v = lh[t];
        lsc[t] = v;
        __syncthreads();
        for (int off = 1; off < THREADS; off <<= 1) {
            int tv = (t >= off) ? lsc[t - off] : 0;
            __syncthreads();
            lsc[t] += tv;
            __syncthreads();
        }
        int base = lsc[t] - v;
        lpos[t] = base;
        __syncthreads();
        for (int e = e0 + t; e < e1; e += THREADS) {
            int dd = dst[e];
            int p = atomicAdd(&lpos[dd >> 8], 1);
            stage[p] = (unsigned int)src[e] | ((unsigned int)(dd & 255) << 16);
        }
        __syncthreads();
        int n = e1 - e0;
        for (int i = t; i < n; i += THREADS) pairs[e0 + i] = stage[i];
        if (t < NB)
            counts[(size_t)blockIdx.x * 256 + t] = ((unsigned int)base << 16) | (unsigned int)v;
        return;
    }
    // zero-row init: p1 has 4 slabs of stride (N+1)*32, p2 has 2
    if (blockIdx.x == NBLK1 && t < 192) {
        int wi = t & 31;
        size_t Np32 = (size_t)(Nn + 1) * 32;
        if (t < 128) p1z[(size_t)(t >> 5) * Np32 + (size_t)Nn * 32 + wi] = 0;
        else         p2z[(size_t)((t - 128) >> 5) * Np32 + (size_t)Nn * 32 + wi] = 0;
    }
    int i = (blockIdx.x - NBLK1) * THREADS + t;
    if (i < nx4) {
        float4 v = ((const float4*)x)[i];
        ushort4 u;
        u.x = f2bf(v.x); u.y = f2bf(v.y); u.z = f2bf(v.z); u.w = f2bf(v.w);
        ((ushort4*)xb)[i] = u;
        return;
    }
    int j = i - nx4;
    if (j >= 49152) return;
    float v;
    if (j < 16384) v = wa[j];
    else if (j < 32768) v = wb[j - 16384];
    else if (j < 40960) v = wc[j - 32768];
    else v = wd[j - 40960];
    Wb[j] = f2bf(v);
}

// ---------------------------------------------------------------------------
// MFMA bf16 GEMM body (R9-proven). pOut tables (gathered later) are padded:
// slab stride (M+1)*32 with row M = zeros. rOut tables unpadded (M*32).
template<int NOUT, bool ASLAB>
static __device__ __forceinline__
void gemm_body(const unsigned short* __restrict__ A, const unsigned short* __restrict__ W0,
               const unsigned short* __restrict__ W1, const float* __restrict__ biasR,
               unsigned short* __restrict__ pOut, unsigned short* __restrict__ rOut,
               int M, int job, int xt) {
    constexpr int CT = 4;
    int outSel, chalf;
    if (NOUT == 128) { outSel = job >> 1; chalf = job & 1; }
    else             { outSel = job;      chalf = 0; }
    const unsigned short* W = (outSel ? W1 : W0) + chalf * 64 * 128;

    const int wv = threadIdx.x >> 6, ln = threadIdx.x & 63;
    const int bl = ln & 15, quad = ln >> 4;
    const int mt = xt * 4 + wv;
    const size_t M32 = (size_t)M * 32;
    const size_t Mp32 = (size_t)(M + 1) * 32;

    ABfrag Bf[CT][4];
    #pragma unroll
    for (int ct = 0; ct < CT; ++ct)
        #pragma unroll
        for (int ks = 0; ks < 4; ++ks)
            Bf[ct][ks].q = *(const uint4*)&W[(size_t)(ct * 16 + bl) * 128 + ks * 32 + quad * 8];

    if (mt * 16 >= M) return;
    const int m0 = mt * 16;
    const int arow = m0 + bl;

    floatx4 acc[CT];
    #pragma unroll
    for (int ct = 0; ct < CT; ++ct) acc[ct] = (floatx4){0.f, 0.f, 0.f, 0.f};

    #pragma unroll
    for (int ks = 0; ks < 4; ++ks) {
        ABfrag Af;
        if (ASLAB) Af.q = *(const uint4*)&A[(size_t)ks * M32 + (size_t)arow * 32 + quad * 8];
        else       Af.q = *(const uint4*)&A[(size_t)arow * 128 + ks * 32 + quad * 8];
        #pragma unroll
        for (int ct = 0; ct < CT; ++ct)
            acc[ct] = __builtin_amdgcn_mfma_f32_16x16x32_bf16(Af.v, Bf[ct][ks].v, acc[ct], 0, 0, 0);
    }

    unsigned short* outp = outSel ? rOut : pOut;
    const size_t ostride = outSel ? M32 : Mp32;
    #pragma unroll
    for (int ct = 0; ct < CT; ++ct) {
        int col = chalf * 64 + ct * 16 + bl;
        int slab = col >> 5, wi = col & 31;
        size_t sbase = (size_t)slab * ostride;
        float bv = outSel ? biasR[col] : 0.f;
        #pragma unroll
        for (int i = 0; i < 4; ++i) {
            int row = m0 + quad * 4 + i;
            outp[sbase + (size_t)row * 32 + wi] = f2bf(acc[ct][i] + bv);
        }
    }
}

// ---------------------------------------------------------------------------
// D2: fused layer-1 GEMM + flat-index CSR finalize.
// grid (gemmBlocks, 5): y>=1 -> gemm job y-1; y==0 && x<NB -> finalize.
__global__ __launch_bounds__(THREADS)
void gemm128_csr(const unsigned short* __restrict__ A, const unsigned short* __restrict__ W0,
                 const unsigned short* __restrict__ W1, const float* __restrict__ biasR,
                 unsigned short* __restrict__ pOut, unsigned short* __restrict__ rOut, int M,
                 const unsigned int* __restrict__ pairs, const unsigned int* __restrict__ counts,
                 int* __restrict__ rowptr, unsigned short* __restrict__ degs,
                 unsigned short* __restrict__ csr, int N, int E, int NB, int chunk) {
    __shared__ int runsrc[NBLK1];
    __shared__ int runbase[NBLK1 + 1];
    __shared__ int lhist[THREADS], lscan[THREADS], loff[THREADS];

    if (blockIdx.y != 0) {
        gemm_body<128, false>(A, W0, W1, biasR, pOut, rOut, M, blockIdx.y - 1, blockIdx.x);
        return;
    }
    int b = blockIdx.x, t = threadIdx.x;
    if (b >= NB) return;

    // per-run {length, source offset} from counts; scan lengths -> runbase
    unsigned int pc0 = counts[(size_t)t * 256 + b];
    unsigned int pc1 = counts[(size_t)(t + 256) * 256 + b];
    int c0 = (int)(pc0 & 0xffffu), c1 = (int)(pc1 & 0xffffu);
    runsrc[t] = t * chunk + (int)(pc0 >> 16);
    runsrc[t + 256] = (t + 256) * chunk + (int)(pc1 >> 16);
    lscan[t] = c0;
    __syncthreads();
    for (int off = 1; off < THREADS; off <<= 1) {
        int xx = (t >= off) ? lscan[t - off] : 0;
        __syncthreads();
        lscan[t] += xx;
        __syncthreads();
    }
    runbase[t] = lscan[t] - c0;
    int S0 = lscan[THREADS - 1];
    __syncthreads();
    lscan[t] = c1;
    __syncthreads();
    for (int off = 1; off < THREADS; off <<= 1) {
        int xx = (t >= off) ? lscan[t - off] : 0;
        __syncthreads();
        lscan[t] += xx;
        __syncthreads();
    }
    runbase[256 + t] = S0 + lscan[t] - c1;
    if (t == THREADS - 1) runbase[512] = S0 + lscan[t];
    lhist[t] = 0;
    __syncthreads();
    int sz = runbase[512];

    // Pass A: flat-index histogram. Each element independent: 9-step LDS
    // binary search for its run, then one global load + one LDS atomic.
    for (int i0 = t; i0 < sz; i0 += 4 * THREADS) {
        unsigned pv[4];
        int ok[4];
        #pragma unroll
        for (int k = 0; k < 4; ++k) {
            int i = i0 + k * THREADS;
            ok[k] = (i < sz);
            int idx = ok[k] ? i : (sz - 1);
            int lo = 0, hi = NBLK1;
            #pragma unroll
            for (int s = 0; s < 9; ++s) {
                int mid = (lo + hi) >> 1;
                bool c = runbase[mid] <= idx;
                lo = c ? mid : lo;
                hi = c ? hi : mid;
            }
            pv[k] = pairs[runsrc[lo] + (idx - runbase[lo])];
        }
        #pragma unroll
        for (int k = 0; k < 4; ++k)
            if (ok[k]) atomicAdd(&lhist[(pv[k] >> 16) & 255], 1);
    }
    __syncthreads();

    // padded (8-aligned) counts -> scan -> rowptr / degs / loff / sentinel pads
    int v = lhist[t];
    int pcv = (v + 7) & ~7;
    lscan[t] = pcv;
    __syncthreads();
    for (int off = 1; off < THREADS; off <<= 1) {
        int xx = (t >= off) ? lscan[t - off] : 0;
        __syncthreads();
        lscan[t] += xx;
        __syncthreads();
    }
    int rel = lscan[t] - pcv;
    int base = b * CSTRIDE + rel;
    int id = (b << 8) + t;
    if (id < N) {
        rowptr[id] = base;
        degs[id] = (unsigned short)v;
    }
    loff[t] = base;
    for (int i = v; i < pcv; ++i) csr[base + i] = (unsigned short)N;  // sentinel -> zero row
    __syncthreads();

    // Pass B: flat-index scatter (pairs L2-warm from pass A).
    for (int i0 = t; i0 < sz; i0 += 4 * THREADS) {
        unsigned pv[4];
        int ok[4];
        #pragma unroll
        for (int k = 0; k < 4; ++k) {
            int i = i0 + k * THREADS;
            ok[k] = (i < sz);
            int idx = ok[k] ? i : (sz - 1);
            int lo = 0, hi = NBLK1;
            #pragma unroll
            for (int s = 0; s < 9; ++s) {
                int mid = (lo + hi) >> 1;
                bool c = runbase[mid] <= idx;
                lo = c ? mid : lo;
                hi = c ? hi : mid;
            }
            pv[k] = pairs[runsrc[lo] + (idx - runbase[lo])];
        }
        #pragma unroll
        for (int k = 0; k < 4; ++k)
            if (ok[k]) {
                int pos = atomicAdd(&loff[(pv[k] >> 16) & 255], 1);
                csr[pos] = (unsigned short)(pv[k] & 0xffffu);
            }
    }
}

// D4: layer-2 GEMM (A = h bf16 slab-major unpadded, p2 out padded).
__global__ __launch_bounds__(THREADS)
void gemm64(const unsigned short* __restrict__ A, const unsigned short* __restrict__ W0,
            const unsigned short* __restrict__ W1, const float* __restrict__ b2,
            unsigned short* __restrict__ p2, unsigned short* __restrict__ r2, int M) {
    gemm_body<64, true>(A, W0, W1, b2, p2, r2, M, blockIdx.y, blockIdx.x);
}

// ---------------------------------------------------------------------------
// D3: gather layer 1. Block = 128 nodes; each 4-lane group owns TWO
// degree-sorted-adjacent nodes -> 16 independent gathers in flight per iter.
// XCD-pinned: slab = (b&7)>>1 so each XCD pair owns one slab (3.2MB in 4MB L2).
__global__ __launch_bounds__(THREADS)
void gather_h(const unsigned short* __restrict__ p1, const int* __restrict__ rowptr,
              const unsigned short* __restrict__ degs, const unsigned short* __restrict__ csr,
              const unsigned short* __restrict__ r1, unsigned short* __restrict__ h,
              int N, int nodeBlocks) {
    __shared__ int sdeg[128], perm[128];
    const size_t N32 = (size_t)N * 32;
    const size_t Np32 = (size_t)(N + 1) * 32;
    int b = blockIdx.x;
    int slab = (b & 7) >> 1;
    int nb = ((b >> 3) << 1) | (b & 1);
    if (nb >= nodeBlocks) return;
    int g0 = nb * 128;
    int t = threadIdx.x;
    if (t < 128) {
        int g = g0 + t;
        sdeg[t] = (g < N) ? (int)degs[g] : -1;
    }
    __syncthreads();
    if (t < 128) {
        int d = sdeg[t], r = 0;
        #pragma unroll 8
        for (int j = 0; j < 128; ++j) {
            int dj = sdeg[j];
            r += (dj < d) || (dj == d && j < t);
        }
        perm[r] = t;
    }
    __syncthreads();
    int grp = t >> 2, lane = t & 3;
    int la = perm[2 * grp], lb = perm[2 * grp + 1];
    int ga = g0 + la, gb = g0 + lb;
    int da = sdeg[la], db = sdeg[lb];
    const unsigned short* ps = p1 + (size_t)slab * Np32;
    int sa = rowptr[min(ga, N - 1)];
    int sb = rowptr[min(gb, N - 1)];
    int na = (da + 7) >> 3, nb2 = (db + 7) >> 3;   // da=-1 -> 0
    int nmax = max(na, nb2);
    const unsigned short* cpa = csr + sa;
    const unsigned short* cpb = csr + sb;
    unsigned SENT2 = ((unsigned)N << 16) | (unsigned)N;
    u32x4 sentv = {SENT2, SENT2, SENT2, SENT2};
    float accA[8] = {0.f, 0.f, 0.f, 0.f, 0.f, 0.f, 0.f, 0.f};
    float accB[8] = {0.f, 0.f, 0.f, 0.f, 0.f, 0.f, 0.f, 0.f};
    for (int it = 0; it < nmax; ++it) {
        u32x4 ca = __builtin_nontemporal_load((const u32x4*)(cpa + min(it, na - 1) * 8));
        u32x4 cb = __builtin_nontemporal_load((const u32x4*)(cpb + min(it, nb2 - 1) * 8));
        if (it >= na) ca = sentv;
        if (it >= nb2) cb = sentv;
        gath8(accA, ps, ca, lane);
        gath8(accB, ps, cb, lane);
    }
    float rca = 1.0f / fmaxf((float)da, 1.0f);
    float rcb = 1.0f / fmaxf((float)db, 1.0f);
    V4 rva, rvb;
    rva.w = __builtin_nontemporal_load((const u32x4*)(r1 + slab * N32 + (size_t)min(ga, N - 1) * 32 + lane * 8));
    rvb.w = __builtin_nontemporal_load((const u32x4*)(r1 + slab * N32 + (size_t)min(gb, N - 1) * 32 + lane * 8));
    float rra[8], rrb[8];
    unpack8(rra, rva.q);
    unpack8(rrb, rvb.q);
    if (ga < N) {
        float o[8];
        #pragma unroll
        for (int i = 0; i < 8; ++i) o[i] = fmaxf(accA[i] * rca + rra[i], 0.f);
        u32x4 u;
        u[0] = (unsigned)f2bf(o[0]) | ((unsigned)f2bf(o[1]) << 16);
        u[1] = (unsigned)f2bf(o[2]) | ((unsigned)f2bf(o[3]) << 16);
        u[2] = (unsigned)f2bf(o[4]) | ((unsigned)f2bf(o[5]) << 16);
        u[3] = (unsigned)f2bf(o[6]) | ((unsigned)f2bf(o[7]) << 16);
        __builtin_nontemporal_store(u, (u32x4*)(h + slab * N32 + (size_t)ga * 32 + lane * 8));
    }
    if (gb < N) {
        float o[8];
        #pragma unroll
        for (int i = 0; i < 8; ++i) o[i] = fmaxf(accB[i] * rcb + rrb[i], 0.f);
        u32x4 u;
        u[0] = (unsigned)f2bf(o[0]) | ((unsigned)f2bf(o[1]) << 16);
        u[1] = (unsigned)f2bf(o[2]) | ((unsigned)f2bf(o[3]) << 16);
        u[2] = (unsigned)f2bf(o[4]) | ((unsigned)f2bf(o[5]) << 16);
        u[3] = (unsigned)f2bf(o[6]) | ((unsigned)f2bf(o[7]) << 16);
        __builtin_nontemporal_store(u, (u32x4*)(h + slab * N32 + (size_t)gb * 32 + lane * 8));
    }
}

// D5: gather layer 2 (final). XCD-pinned: slab = (b&7)>>2 (4 XCDs per slab).
__global__ __launch_bounds__(THREADS)
void gather_out(const unsigned short* __restrict__ p2, const int* __restrict__ rowptr,
                const unsigned short* __restrict__ degs, const unsigned short* __restrict__ csr,
                const unsigned short* __restrict__ r2, float* __restrict__ out,
                int N, int nodeBlocks) {
    __shared__ int sdeg[128], perm[128];
    const size_t N32 = (size_t)N * 32;
    const size_t Np32 = (size_t)(N + 1) * 32;
    int b = blockIdx.x;
    int slab = (b & 7) >> 2;
    int nb = ((b >> 3) << 2) | (b & 3);
    if (nb >= nodeBlocks) return;
    int g0 = nb * 128;
    int t = threadIdx.x;
    if (t < 128) {
        int g = g0 + t;
        sdeg[t] = (g < N) ? (int)degs[g] : -1;
    }
    __syncthreads();
    if (t < 128) {
        int d = sdeg[t], r = 0;
        #pragma unroll 8
        for (int j = 0; j < 128; ++j) {
            int dj = sdeg[j];
            r += (dj < d) || (dj == d && j < t);
        }
        perm[r] = t;
    }
    __syncthreads();
    int grp = t >> 2, lane = t & 3;
    int la = perm[2 * grp], lb = perm[2 * grp + 1];
    int ga = g0 + la, gb = g0 + lb;
    int da = sdeg[la], db = sdeg[lb];
    const unsigned short* ps = p2 + (size_t)slab * Np32;
    int sa = rowptr[min(ga, N - 1)];
    int sb = rowptr[min(gb, N - 1)];
    int na = (da + 7) >> 3, nb2 = (db + 7) >> 3;
    int nmax = max(na, nb2);
    const unsigned short* cpa = csr + sa;
    const unsigned short* cpb = csr + sb;
    unsigned SENT2 = ((unsigned)N << 16) | (unsigned)N;
    u32x4 sentv = {SENT2, SENT2, SENT2, SENT2};
    float accA[8] = {0.f, 0.f, 0.f, 0.f, 0.f, 0.f, 0.f, 0.f};
    float accB[8] = {0.f, 0.f, 0.f, 0.f, 0.f, 0.f, 0.f, 0.f};
    for (int it = 0; it < nmax; ++it) {
        u32x4 ca = __builtin_nontemporal_load((const u32x4*)(cpa + min(it, na - 1) * 8));
        u32x4 cb = __builtin_nontemporal_load((const u32x4*)(cpb + min(it, nb2 - 1) * 8));
        if (it >= na) ca = sentv;
        if (it >= nb2) cb = sentv;
        gath8(accA, ps, ca, lane);
        gath8(accB, ps, cb, lane);
    }
    float rca = 1.0f / fmaxf((float)da, 1.0f);
    float rcb = 1.0f / fmaxf((float)db, 1.0f);
    V4 rva, rvb;
    rva.w = __builtin_nontemporal_load((const u32x4*)(r2 + slab * N32 + (size_t)min(ga, N - 1) * 32 + lane * 8));
    rvb.w = __builtin_nontemporal_load((const u32x4*)(r2 + slab * N32 + (size_t)min(gb, N - 1) * 32 + lane * 8));
    float rra[8], rrb[8];
    unpack8(rra, rva.q);
    unpack8(rrb, rvb.q);
    if (ga < N) {
        f32x4 o0, o1;
        #pragma unroll
        for (int i = 0; i < 4; ++i) o0[i] = accA[i] * rca + rra[i];
        #pragma unroll
        for (int i = 0; i < 4; ++i) o1[i] = accA[4 + i] * rca + rra[4 + i];
        f32x4* o4 = (f32x4*)(out + (size_t)ga * 64 + slab * 32 + lane * 8);
        __builtin_nontemporal_store(o0, o4);
        __builtin_nontemporal_store(o1, o4 + 1);
    }
    if (gb < N) {
        f32x4 o0, o1;
        #pragma unroll
        for (int i = 0; i < 4; ++i) o0[i] = accB[i] * rcb + rrb[i];
        #pragma unroll
        for (int i = 0; i < 4; ++i) o1[i] = accB[4 + i] * rcb + rrb[4 + i];
        f32x4* o4 = (f32x4*)(out + (size_t)gb * 64 + slab * 32 + lane * 8);
        __builtin_nontemporal_store(o0, o4);
        __builtin_nontemporal_store(o1, o4 + 1);
    }
}

// ---------------------------------------------------------------------------
extern "C" void kernel_launch(void* const* d_in, const int* in_sizes, int n_in,
                              void* d_out, int out_size, void* d_ws, size_t ws_size,
                              hipStream_t stream) {
    const float* x   = (const float*)d_in[0];
    const int* edges = (const int*)d_in[1];
    const float* Wl1 = (const float*)d_in[2];
    const float* Wr1 = (const float*)d_in[3];
    const float* b1  = (const float*)d_in[4];
    const float* Wl2 = (const float*)d_in[5];
    const float* Wr2 = (const float*)d_in[6];
    const float* b2  = (const float*)d_in[7];
    float* out = (float*)d_out;

    const int N = in_sizes[0] / 128;     // 50000 (< 65536)
    const int E = in_sizes[1] / 2;       // 1600000
    const int NB = (N + 255) >> 8;       // 196
    const int chunk = (E + NBLK1 - 1) / NBLK1;   // 3125
    const int* src = edges;
    const int* dstv = edges + E;

    // Workspace (slab-major tables; p1/p2 padded with zero row N)
    char* wsp = (char*)d_ws;
    unsigned short* p1  = (unsigned short*)wsp;  wsp += (size_t)(N + 1) * 128 * 2;
    unsigned short* r1  = (unsigned short*)wsp;  wsp += (size_t)N * 128 * 2;
    unsigned short* h   = (unsigned short*)wsp;  wsp += (size_t)N * 128 * 2;
    unsigned short* p2  = (unsigned short*)wsp;  wsp += (size_t)(N + 1) * 64 * 2;
    unsigned short* r2  = (unsigned short*)wsp;  wsp += (size_t)N * 64 * 2;
    unsigned short* xb  = (unsigned short*)wsp;  wsp += (size_t)N * 128 * 2;
    unsigned int* pairs = (unsigned int*)wsp;    wsp += (size_t)E * 4;
    unsigned short* csr = (unsigned short*)wsp;  wsp += (size_t)NB * CSTRIDE * 2;  // 4.8 MB
    unsigned short* Wb  = (unsigned short*)wsp;  wsp += (size_t)49152 * 2;
    unsigned int* counts= (unsigned int*)wsp;    wsp += (size_t)NBLK1 * 256 * 4;
    int* rowptr         = (int*)wsp;             wsp += (size_t)(N + 1) * 4;
    unsigned short* degs= (unsigned short*)wsp;  wsp += (size_t)((N + 1) & ~1) * 2;

    unsigned short* Wl1b = Wb;
    unsigned short* Wr1b = Wb + 16384;
    unsigned short* Wl2b = Wb + 32768;
    unsigned short* Wr2b = Wb + 40960;

    const int nx4 = N * 128 / 4;
    const int castBlocks = (nx4 + 49152 + THREADS - 1) / THREADS;
    const int MT = (N + 15) / 16;                 // 3125
    const int gemmBlocks = (MT + 3) / 4;          // 782
    const int nodeBlocks = (N + 127) / 128;       // 391

    // D1: fused cast + CSR part1 + zero-row init
    fused_cast_p1<<<NBLK1 + castBlocks, THREADS, 0, stream>>>(
        x, Wl1, Wr1, Wl2, Wr2, xb, Wb, nx4, src, dstv, pairs, counts, E, chunk, NB,
        p1, p2, N);

    // D2: layer-1 GEMM (4 jobs) + flat-index CSR finalize (y==0)
    gemm128_csr<<<dim3(gemmBlocks, 5), THREADS, 0, stream>>>(
        xb, Wl1b, Wr1b, b1, p1, r1, N,
        pairs, counts, rowptr, degs, csr, N, E, NB, chunk);

    // D3: gather layer 1 (4 slabs, XCD-pinned: 2 XCDs per slab)
    gather_h<<<8 * ((nodeBlocks + 1) / 2), THREADS, 0, stream>>>(
        p1, rowptr, degs, csr, r1, h, N, nodeBlocks);

    // D4: layer-2 GEMM
    gemm64<<<dim3(gemmBlocks, 2), THREADS, 0, stream>>>(h, Wl2b, Wr2b, b2, p2, r2, N);

    // D5: gather layer 2 -> final output (2 slabs, XCD-pinned: 4 XCDs per slab)
    gather_out<<<8 * ((nodeBlocks + 3) / 4), THREADS, 0, stream>>>(
        p2, rowptr, degs, csr, r2, out, N, nodeBlocks);
}

// Round 5
// 256.752 us; speedup vs baseline: 1.1790x; 1.0718x over previous
//
#include <hip/hip_runtime.h>
#include <hip/hip_bf16.h>

// GraphSAGE 2-layer forward.
// R19 = R18 with the gather TLP restored (H1 test):
//  - R18 post-mortem: XCD pinning crushed FETCH 236->45MB (keep it), but
//    dur stayed ~70us: the 128-node-pair blocks cut the grid to 6.3k waves
//    (no backfill) and the degree sort gave wave0 the lowest 32 ranks and
//    wave3 the highest -> unbalanced drain, Occupancy 27%.
//  - Revert to 1 node per 4-lane group, 64-node blocks (R16 loop body:
//    sentinel-padded csr, uniform 8-wide, no clamping). gather_h grid =
//    3128 blocks = 12.5k waves -> full residency + backfill; ~256 scattered
//    requests outstanding per CU.
//  - Keep: XCD-pair pinning (slab=(b&7)>>1), flat-index finalize, padded
//    csr + zero row, degree sort within 64-node blocks.

#define THREADS 256
#define NBLK1 512          // csr part1 blocks (chunk = 3125 <= 3328 stage cap)
#define CSTRIDE 12288      // padded csr entries per 256-node bucket

typedef __bf16 bf16x8 __attribute__((ext_vector_type(8)));
typedef float floatx4 __attribute__((ext_vector_type(4)));
typedef float f32x4 __attribute__((ext_vector_type(4)));
typedef unsigned int u32x4 __attribute__((ext_vector_type(4)));

union ABfrag { bf16x8 v; unsigned short u[8]; uint4 q; };
union V4 { u32x4 w; uint4 q; };

static __device__ __forceinline__ unsigned short f2bf(float f) {
    unsigned int u = __float_as_uint(f);
    u = (u + 0x7fffu + ((u >> 16) & 1u)) >> 16;   // RNE
    return (unsigned short)u;
}

static __device__ __forceinline__ void unpack8(float* o, uint4 v) {
    o[0] = __uint_as_float(v.x << 16);
    o[1] = __uint_as_float(v.x & 0xffff0000u);
    o[2] = __uint_as_float(v.y << 16);
    o[3] = __uint_as_float(v.y & 0xffff0000u);
    o[4] = __uint_as_float(v.z << 16);
    o[5] = __uint_as_float(v.z & 0xffff0000u);
    o[6] = __uint_as_float(v.w << 16);
    o[7] = __uint_as_float(v.w & 0xffff0000u);
}

static __device__ __forceinline__ void acc8(float* acc, uint4 v) {
    float t[8];
    unpack8(t, v);
    #pragma unroll
    for (int i = 0; i < 8; ++i) acc[i] += t[i];
}

// 8 gathers from one packed csr vector (indices s0..s7), accumulate.
static __device__ __forceinline__ void gath8(float* acc, const unsigned short* __restrict__ ps,
                                             u32x4 c, int lane) {
    unsigned s0 = c[0] & 0xffffu, s1 = c[0] >> 16;
    unsigned s2 = c[1] & 0xffffu, s3 = c[1] >> 16;
    unsigned s4 = c[2] & 0xffffu, s5 = c[2] >> 16;
    unsigned s6 = c[3] & 0xffffu, s7 = c[3] >> 16;
    acc8(acc, *(const uint4*)&ps[(size_t)s0 * 32 + lane * 8]);
    acc8(acc, *(const uint4*)&ps[(size_t)s1 * 32 + lane * 8]);
    acc8(acc, *(const uint4*)&ps[(size_t)s2 * 32 + lane * 8]);
    acc8(acc, *(const uint4*)&ps[(size_t)s3 * 32 + lane * 8]);
    acc8(acc, *(const uint4*)&ps[(size_t)s4 * 32 + lane * 8]);
    acc8(acc, *(const uint4*)&ps[(size_t)s5 * 32 + lane * 8]);
    acc8(acc, *(const uint4*)&ps[(size_t)s6 * 32 + lane * 8]);
    acc8(acc, *(const uint4*)&ps[(size_t)s7 * 32 + lane * 8]);
}

// ---------------------------------------------------------------------------
// D1: fused cast (x->bf16, W->bf16) + CSR part1 + zero-row init for p1/p2.
__global__ __launch_bounds__(THREADS)
void fused_cast_p1(const float* __restrict__ x, const float* __restrict__ wa,
                   const float* __restrict__ wb, const float* __restrict__ wc,
                   const float* __restrict__ wd, unsigned short* __restrict__ xb,
                   unsigned short* __restrict__ Wb, int nx4,
                   const int* __restrict__ src, const int* __restrict__ dst,
                   unsigned int* __restrict__ pairs, unsigned int* __restrict__ counts,
                   int E, int chunk, int NB,
                   unsigned short* __restrict__ p1z, unsigned short* __restrict__ p2z, int Nn) {
    __shared__ int lh[THREADS], lsc[THREADS], lpos[THREADS];
    __shared__ unsigned int stage[3328];
    int t = threadIdx.x;
    if (blockIdx.x < NBLK1) {
        int e0 = blockIdx.x * chunk, e1 = min(E, e0 + chunk);
        lh[t] = 0;
        __syncthreads();
        for (int e = e0 + t; e < e1; e += THREADS) atomicAdd(&lh[dst[e] >> 8], 1);
        __syncthreads();
        int v = lh[t];
        lsc[t] = v;
        __syncthreads();
        for (int off = 1; off < THREADS; off <<= 1) {
            int tv = (t >= off) ? lsc[t - off] : 0;
            __syncthreads();
            lsc[t] += tv;
            __syncthreads();
        }
        int base = lsc[t] - v;
        lpos[t] = base;
        __syncthreads();
        for (int e = e0 + t; e < e1; e += THREADS) {
            int dd = dst[e];
            int p = atomicAdd(&lpos[dd >> 8], 1);
            stage[p] = (unsigned int)src[e] | ((unsigned int)(dd & 255) << 16);
        }
        __syncthreads();
        int n = e1 - e0;
        for (int i = t; i < n; i += THREADS) pairs[e0 + i] = stage[i];
        if (t < NB)
            counts[(size_t)blockIdx.x * 256 + t] = ((unsigned int)base << 16) | (unsigned int)v;
        return;
    }
    // zero-row init: p1 has 4 slabs of stride (N+1)*32, p2 has 2
    if (blockIdx.x == NBLK1 && t < 192) {
        int wi = t & 31;
        size_t Np32 = (size_t)(Nn + 1) * 32;
        if (t < 128) p1z[(size_t)(t >> 5) * Np32 + (size_t)Nn * 32 + wi] = 0;
        else         p2z[(size_t)((t - 128) >> 5) * Np32 + (size_t)Nn * 32 + wi] = 0;
    }
    int i = (blockIdx.x - NBLK1) * THREADS + t;
    if (i < nx4) {
        float4 v = ((const float4*)x)[i];
        ushort4 u;
        u.x = f2bf(v.x); u.y = f2bf(v.y); u.z = f2bf(v.z); u.w = f2bf(v.w);
        ((ushort4*)xb)[i] = u;
        return;
    }
    int j = i - nx4;
    if (j >= 49152) return;
    float v;
    if (j < 16384) v = wa[j];
    else if (j < 32768) v = wb[j - 16384];
    else if (j < 40960) v = wc[j - 32768];
    else v = wd[j - 40960];
    Wb[j] = f2bf(v);
}

// ---------------------------------------------------------------------------
// MFMA bf16 GEMM body (R9-proven). pOut tables (gathered later) are padded:
// slab stride (M+1)*32 with row M = zeros. rOut tables unpadded (M*32).
template<int NOUT, bool ASLAB>
static __device__ __forceinline__
void gemm_body(const unsigned short* __restrict__ A, const unsigned short* __restrict__ W0,
               const unsigned short* __restrict__ W1, const float* __restrict__ biasR,
               unsigned short* __restrict__ pOut, unsigned short* __restrict__ rOut,
               int M, int job, int xt) {
    constexpr int CT = 4;
    int outSel, chalf;
    if (NOUT == 128) { outSel = job >> 1; chalf = job & 1; }
    else             { outSel = job;      chalf = 0; }
    const unsigned short* W = (outSel ? W1 : W0) + chalf * 64 * 128;

    const int wv = threadIdx.x >> 6, ln = threadIdx.x & 63;
    const int bl = ln & 15, quad = ln >> 4;
    const int mt = xt * 4 + wv;
    const size_t M32 = (size_t)M * 32;
    const size_t Mp32 = (size_t)(M + 1) * 32;

    ABfrag Bf[CT][4];
    #pragma unroll
    for (int ct = 0; ct < CT; ++ct)
        #pragma unroll
        for (int ks = 0; ks < 4; ++ks)
            Bf[ct][ks].q = *(const uint4*)&W[(size_t)(ct * 16 + bl) * 128 + ks * 32 + quad * 8];

    if (mt * 16 >= M) return;
    const int m0 = mt * 16;
    const int arow = m0 + bl;

    floatx4 acc[CT];
    #pragma unroll
    for (int ct = 0; ct < CT; ++ct) acc[ct] = (floatx4){0.f, 0.f, 0.f, 0.f};

    #pragma unroll
    for (int ks = 0; ks < 4; ++ks) {
        ABfrag Af;
        if (ASLAB) Af.q = *(const uint4*)&A[(size_t)ks * M32 + (size_t)arow * 32 + quad * 8];
        else       Af.q = *(const uint4*)&A[(size_t)arow * 128 + ks * 32 + quad * 8];
        #pragma unroll
        for (int ct = 0; ct < CT; ++ct)
            acc[ct] = __builtin_amdgcn_mfma_f32_16x16x32_bf16(Af.v, Bf[ct][ks].v, acc[ct], 0, 0, 0);
    }

    unsigned short* outp = outSel ? rOut : pOut;
    const size_t ostride = outSel ? M32 : Mp32;
    #pragma unroll
    for (int ct = 0; ct < CT; ++ct) {
        int col = chalf * 64 + ct * 16 + bl;
        int slab = col >> 5, wi = col & 31;
        size_t sbase = (size_t)slab * ostride;
        float bv = outSel ? biasR[col] : 0.f;
        #pragma unroll
        for (int i = 0; i < 4; ++i) {
            int row = m0 + quad * 4 + i;
            outp[sbase + (size_t)row * 32 + wi] = f2bf(acc[ct][i] + bv);
        }
    }
}

// ---------------------------------------------------------------------------
// D2: fused layer-1 GEMM + flat-index CSR finalize.
// grid (gemmBlocks, 5): y>=1 -> gemm job y-1; y==0 && x<NB -> finalize.
__global__ __launch_bounds__(THREADS)
void gemm128_csr(const unsigned short* __restrict__ A, const unsigned short* __restrict__ W0,
                 const unsigned short* __restrict__ W1, const float* __restrict__ biasR,
                 unsigned short* __restrict__ pOut, unsigned short* __restrict__ rOut, int M,
                 const unsigned int* __restrict__ pairs, const unsigned int* __restrict__ counts,
                 int* __restrict__ rowptr, unsigned short* __restrict__ degs,
                 unsigned short* __restrict__ csr, int N, int E, int NB, int chunk) {
    __shared__ int runsrc[NBLK1];
    __shared__ int runbase[NBLK1 + 1];
    __shared__ int lhist[THREADS], lscan[THREADS], loff[THREADS];

    if (blockIdx.y != 0) {
        gemm_body<128, false>(A, W0, W1, biasR, pOut, rOut, M, blockIdx.y - 1, blockIdx.x);
        return;
    }
    int b = blockIdx.x, t = threadIdx.x;
    if (b >= NB) return;

    // per-run {length, source offset} from counts; scan lengths -> runbase
    unsigned int pc0 = counts[(size_t)t * 256 + b];
    unsigned int pc1 = counts[(size_t)(t + 256) * 256 + b];
    int c0 = (int)(pc0 & 0xffffu), c1 = (int)(pc1 & 0xffffu);
    runsrc[t] = t * chunk + (int)(pc0 >> 16);
    runsrc[t + 256] = (t + 256) * chunk + (int)(pc1 >> 16);
    lscan[t] = c0;
    __syncthreads();
    for (int off = 1; off < THREADS; off <<= 1) {
        int xx = (t >= off) ? lscan[t - off] : 0;
        __syncthreads();
        lscan[t] += xx;
        __syncthreads();
    }
    runbase[t] = lscan[t] - c0;
    int S0 = lscan[THREADS - 1];
    __syncthreads();
    lscan[t] = c1;
    __syncthreads();
    for (int off = 1; off < THREADS; off <<= 1) {
        int xx = (t >= off) ? lscan[t - off] : 0;
        __syncthreads();
        lscan[t] += xx;
        __syncthreads();
    }
    runbase[256 + t] = S0 + lscan[t] - c1;
    if (t == THREADS - 1) runbase[512] = S0 + lscan[t];
    lhist[t] = 0;
    __syncthreads();
    int sz = runbase[512];

    // Pass A: flat-index histogram. Each element independent: 9-step LDS
    // binary search for its run, then one global load + one LDS atomic.
    for (int i0 = t; i0 < sz; i0 += 4 * THREADS) {
        unsigned pv[4];
        int ok[4];
        #pragma unroll
        for (int k = 0; k < 4; ++k) {
            int i = i0 + k * THREADS;
            ok[k] = (i < sz);
            int idx = ok[k] ? i : (sz - 1);
            int lo = 0, hi = NBLK1;
            #pragma unroll
            for (int s = 0; s < 9; ++s) {
                int mid = (lo + hi) >> 1;
                bool c = runbase[mid] <= idx;
                lo = c ? mid : lo;
                hi = c ? hi : mid;
            }
            pv[k] = pairs[runsrc[lo] + (idx - runbase[lo])];
        }
        #pragma unroll
        for (int k = 0; k < 4; ++k)
            if (ok[k]) atomicAdd(&lhist[(pv[k] >> 16) & 255], 1);
    }
    __syncthreads();

    // padded (8-aligned) counts -> scan -> rowptr / degs / loff / sentinel pads
    int v = lhist[t];
    int pcv = (v + 7) & ~7;
    lscan[t] = pcv;
    __syncthreads();
    for (int off = 1; off < THREADS; off <<= 1) {
        int xx = (t >= off) ? lscan[t - off] : 0;
        __syncthreads();
        lscan[t] += xx;
        __syncthreads();
    }
    int rel = lscan[t] - pcv;
    int base = b * CSTRIDE + rel;
    int id = (b << 8) + t;
    if (id < N) {
        rowptr[id] = base;
        degs[id] = (unsigned short)v;
    }
    loff[t] = base;
    for (int i = v; i < pcv; ++i) csr[base + i] = (unsigned short)N;  // sentinel -> zero row
    __syncthreads();

    // Pass B: flat-index scatter (pairs L2-warm from pass A).
    for (int i0 = t; i0 < sz; i0 += 4 * THREADS) {
        unsigned pv[4];
        int ok[4];
        #pragma unroll
        for (int k = 0; k < 4; ++k) {
            int i = i0 + k * THREADS;
            ok[k] = (i < sz);
            int idx = ok[k] ? i : (sz - 1);
            int lo = 0, hi = NBLK1;
            #pragma unroll
            for (int s = 0; s < 9; ++s) {
                int mid = (lo + hi) >> 1;
                bool c = runbase[mid] <= idx;
                lo = c ? mid : lo;
                hi = c ? hi : mid;
            }
            pv[k] = pairs[runsrc[lo] + (idx - runbase[lo])];
        }
        #pragma unroll
        for (int k = 0; k < 4; ++k)
            if (ok[k]) {
                int pos = atomicAdd(&loff[(pv[k] >> 16) & 255], 1);
                csr[pos] = (unsigned short)(pv[k] & 0xffffu);
            }
    }
}

// D4: layer-2 GEMM (A = h bf16 slab-major unpadded, p2 out padded).
__global__ __launch_bounds__(THREADS)
void gemm64(const unsigned short* __restrict__ A, const unsigned short* __restrict__ W0,
            const unsigned short* __restrict__ W1, const float* __restrict__ b2,
            unsigned short* __restrict__ p2, unsigned short* __restrict__ r2, int M) {
    gemm_body<64, true>(A, W0, W1, b2, p2, r2, M, blockIdx.y, blockIdx.x);
}

// ---------------------------------------------------------------------------
// D3: gather layer 1. 64-node blocks, 1 node per 4-lane group, sentinel-
// padded uniform 8-wide loop. XCD-pinned: slab = (b&7)>>1 (XCD pair/slab).
__global__ __launch_bounds__(THREADS)
void gather_h(const unsigned short* __restrict__ p1, const int* __restrict__ rowptr,
              const unsigned short* __restrict__ degs, const unsigned short* __restrict__ csr,
              const unsigned short* __restrict__ r1, unsigned short* __restrict__ h,
              int N, int nodeBlocks) {
    __shared__ int sdeg[64], perm[64];
    const size_t N32 = (size_t)N * 32;
    const size_t Np32 = (size_t)(N + 1) * 32;
    int b = blockIdx.x;
    int slab = (b & 7) >> 1;
    int nb = ((b >> 3) << 1) | (b & 1);
    if (nb >= nodeBlocks) return;
    int g0 = nb * 64;
    int t = threadIdx.x;
    if (t < 64) {
        int g = g0 + t;
        sdeg[t] = (g < N) ? (int)degs[g] : -1;
    }
    __syncthreads();
    if (t < 64) {
        int d = sdeg[t], r = 0;
        #pragma unroll 8
        for (int j = 0; j < 64; ++j) {
            int dj = sdeg[j];
            r += (dj < d) || (dj == d && j < t);
        }
        perm[r] = t;
    }
    __syncthreads();
    int g = g0 + perm[t >> 2];
    if (g >= N) return;
    int lane = t & 3;
    const unsigned short* ps = p1 + (size_t)slab * Np32;
    int start = rowptr[g];
    int deg = degs[g];
    int niter = (deg + 7) >> 3;
    V4 rv;
    rv.w = __builtin_nontemporal_load((const u32x4*)(r1 + slab * N32 + (size_t)g * 32 + lane * 8));
    float acc[8] = {0.f, 0.f, 0.f, 0.f, 0.f, 0.f, 0.f, 0.f};
    const unsigned short* cp = csr + start;   // 16B aligned by construction
    for (int it = 0; it < niter; ++it) {
        u32x4 c = __builtin_nontemporal_load((const u32x4*)(cp + it * 8));
        gath8(acc, ps, c, lane);
    }
    float rc = 1.0f / fmaxf((float)deg, 1.0f);
    float rr[8];
    unpack8(rr, rv.q);
    float o[8];
    #pragma unroll
    for (int i = 0; i < 8; ++i) o[i] = fmaxf(acc[i] * rc + rr[i], 0.f);
    u32x4 u;
    u[0] = (unsigned)f2bf(o[0]) | ((unsigned)f2bf(o[1]) << 16);
    u[1] = (unsigned)f2bf(o[2]) | ((unsigned)f2bf(o[3]) << 16);
    u[2] = (unsigned)f2bf(o[4]) | ((unsigned)f2bf(o[5]) << 16);
    u[3] = (unsigned)f2bf(o[6]) | ((unsigned)f2bf(o[7]) << 16);
    __builtin_nontemporal_store(u, (u32x4*)(h + slab * N32 + (size_t)g * 32 + lane * 8));
}

// D5: gather layer 2 (final). 64-node blocks, 1 node per group.
// XCD-pinned: slab = (b&7)>>2 (XCD quad per slab).
__global__ __launch_bounds__(THREADS)
void gather_out(const unsigned short* __restrict__ p2, const int* __restrict__ rowptr,
                const unsigned short* __restrict__ degs, const unsigned short* __restrict__ csr,
                const unsigned short* __restrict__ r2, float* __restrict__ out,
                int N, int nodeBlocks) {
    __shared__ int sdeg[64], perm[64];
    const size_t N32 = (size_t)N * 32;
    const size_t Np32 = (size_t)(N + 1) * 32;
    int b = blockIdx.x;
    int slab = (b & 7) >> 2;
    int nb = ((b >> 3) << 2) | (b & 3);
    if (nb >= nodeBlocks) return;
    int g0 = nb * 64;
    int t = threadIdx.x;
    if (t < 64) {
        int g = g0 + t;
        sdeg[t] = (g < N) ? (int)degs[g] : -1;
    }
    __syncthreads();
    if (t < 64) {
        int d = sdeg[t], r = 0;
        #pragma unroll 8
        for (int j = 0; j < 64; ++j) {
            int dj = sdeg[j];
            r += (dj < d) || (dj == d && j < t);
        }
        perm[r] = t;
    }
    __syncthreads();
    int g = g0 + perm[t >> 2];
    if (g >= N) return;
    int lane = t & 3;
    const unsigned short* ps = p2 + (size_t)slab * Np32;
    int start = rowptr[g];
    int deg = degs[g];
    int niter = (deg + 7) >> 3;
    V4 rv;
    rv.w = __builtin_nontemporal_load((const u32x4*)(r2 + slab * N32 + (size_t)g * 32 + lane * 8));
    float acc[8] = {0.f, 0.f, 0.f, 0.f, 0.f, 0.f, 0.f, 0.f};
    const unsigned short* cp = csr + start;
    for (int it = 0; it < niter; ++it) {
        u32x4 c = __builtin_nontemporal_load((const u32x4*)(cp + it * 8));
        gath8(acc, ps, c, lane);
    }
    float rc = 1.0f / fmaxf((float)deg, 1.0f);
    float rr[8];
    unpack8(rr, rv.q);
    f32x4 o0, o1;
    #pragma unroll
    for (int i = 0; i < 4; ++i) o0[i] = acc[i] * rc + rr[i];
    #pragma unroll
    for (int i = 0; i < 4; ++i) o1[i] = acc[4 + i] * rc + rr[4 + i];
    f32x4* o4 = (f32x4*)(out + (size_t)g * 64 + slab * 32 + lane * 8);
    __builtin_nontemporal_store(o0, o4);
    __builtin_nontemporal_store(o1, o4 + 1);
}

// ---------------------------------------------------------------------------
extern "C" void kernel_launch(void* const* d_in, const int* in_sizes, int n_in,
                              void* d_out, int out_size, void* d_ws, size_t ws_size,
                              hipStream_t stream) {
    const float* x   = (const float*)d_in[0];
    const int* edges = (const int*)d_in[1];
    const float* Wl1 = (const float*)d_in[2];
    const float* Wr1 = (const float*)d_in[3];
    const float* b1  = (const float*)d_in[4];
    const float* Wl2 = (const float*)d_in[5];
    const float* Wr2 = (const float*)d_in[6];
    const float* b2  = (const float*)d_in[7];
    float* out = (float*)d_out;

    const int N = in_sizes[0] / 128;     // 50000 (< 65536)
    const int E = in_sizes[1] / 2;       // 1600000
    const int NB = (N + 255) >> 8;       // 196
    const int chunk = (E + NBLK1 - 1) / NBLK1;   // 3125
    const int* src = edges;
    const int* dstv = edges + E;

    // Workspace (slab-major tables; p1/p2 padded with zero row N)
    char* wsp = (char*)d_ws;
    unsigned short* p1  = (unsigned short*)wsp;  wsp += (size_t)(N + 1) * 128 * 2;
    unsigned short* r1  = (unsigned short*)wsp;  wsp += (size_t)N * 128 * 2;
    unsigned short* h   = (unsigned short*)wsp;  wsp += (size_t)N * 128 * 2;
    unsigned short* p2  = (unsigned short*)wsp;  wsp += (size_t)(N + 1) * 64 * 2;
    unsigned short* r2  = (unsigned short*)wsp;  wsp += (size_t)N * 64 * 2;
    unsigned short* xb  = (unsigned short*)wsp;  wsp += (size_t)N * 128 * 2;
    unsigned int* pairs = (unsigned int*)wsp;    wsp += (size_t)E * 4;
    unsigned short* csr = (unsigned short*)wsp;  wsp += (size_t)NB * CSTRIDE * 2;  // 4.8 MB
    unsigned short* Wb  = (unsigned short*)wsp;  wsp += (size_t)49152 * 2;
    unsigned int* counts= (unsigned int*)wsp;    wsp += (size_t)NBLK1 * 256 * 4;
    int* rowptr         = (int*)wsp;             wsp += (size_t)(N + 1) * 4;
    unsigned short* degs= (unsigned short*)wsp;  wsp += (size_t)((N + 1) & ~1) * 2;

    unsigned short* Wl1b = Wb;
    unsigned short* Wr1b = Wb + 16384;
    unsigned short* Wl2b = Wb + 32768;
    unsigned short* Wr2b = Wb + 40960;

    const int nx4 = N * 128 / 4;
    const int castBlocks = (nx4 + 49152 + THREADS - 1) / THREADS;
    const int MT = (N + 15) / 16;                 // 3125
    const int gemmBlocks = (MT + 3) / 4;          // 782
    const int nodeBlocks = (N + 63) / 64;         // 782

    // D1: fused cast + CSR part1 + zero-row init
    fused_cast_p1<<<NBLK1 + castBlocks, THREADS, 0, stream>>>(
        x, Wl1, Wr1, Wl2, Wr2, xb, Wb, nx4, src, dstv, pairs, counts, E, chunk, NB,
        p1, p2, N);

    // D2: layer-1 GEMM (4 jobs) + flat-index CSR finalize (y==0)
    gemm128_csr<<<dim3(gemmBlocks, 5), THREADS, 0, stream>>>(
        xb, Wl1b, Wr1b, b1, p1, r1, N,
        pairs, counts, rowptr, degs, csr, N, E, NB, chunk);

    // D3: gather layer 1 (4 slabs, XCD-pinned: 2 XCDs per slab)
    gather_h<<<8 * ((nodeBlocks + 1) / 2), THREADS, 0, stream>>>(
        p1, rowptr, degs, csr, r1, h, N, nodeBlocks);

    // D4: layer-2 GEMM
    gemm64<<<dim3(gemmBlocks, 2), THREADS, 0, stream>>>(h, Wl2b, Wr2b, b2, p2, r2, N);

    // D5: gather layer 2 -> final output (2 slabs, XCD-pinned: 4 XCDs per slab)
    gather_out<<<8 * ((nodeBlocks + 3) / 4), THREADS, 0, stream>>>(
        p2, rowptr, degs, csr, r2, out, N, nodeBlocks);
}

// Round 6
// 250.386 us; speedup vs baseline: 1.2090x; 1.0254x over previous
//
#include <hip/hip_runtime.h>
#include <hip/hip_bf16.h>

// GraphSAGE 2-layer forward.
// R20 = R19 + explicit 16-deep gather MLP (grid/TLP unchanged):
//  - R19 post-mortem: gather_h latency-bound at 57us, ~2x over composed
//    floor (TA-issue ~12us, L2 ~13us, VALU ~7us). Only 8 gathers in
//    flight per 4-lane group. R18 proved MLP alone isn't enough when it
//    costs TLP; R20 raises MLP with the SAME 3128-block grid: edge loop
//    unrolled x2 via gath16() that loads 2 csr vectors and issues all 16
//    row-gathers into registers BEFORE any accumulate (guaranteed 16
//    outstanding per group), tail iteration for odd niter. Degree sort
//    keeps pair-trip-counts wave-uniform.
//  - Everything else identical to R19 (XCD pinning, flat finalize,
//    sentinel-padded csr, zero row).

#define THREADS 256
#define NBLK1 512          // csr part1 blocks (chunk = 3125 <= 3328 stage cap)
#define CSTRIDE 12288      // padded csr entries per 256-node bucket

typedef __bf16 bf16x8 __attribute__((ext_vector_type(8)));
typedef float floatx4 __attribute__((ext_vector_type(4)));
typedef float f32x4 __attribute__((ext_vector_type(4)));
typedef unsigned int u32x4 __attribute__((ext_vector_type(4)));

union ABfrag { bf16x8 v; unsigned short u[8]; uint4 q; };
union V4 { u32x4 w; uint4 q; };

static __device__ __forceinline__ unsigned short f2bf(float f) {
    unsigned int u = __float_as_uint(f);
    u = (u + 0x7fffu + ((u >> 16) & 1u)) >> 16;   // RNE
    return (unsigned short)u;
}

static __device__ __forceinline__ void unpack8(float* o, uint4 v) {
    o[0] = __uint_as_float(v.x << 16);
    o[1] = __uint_as_float(v.x & 0xffff0000u);
    o[2] = __uint_as_float(v.y << 16);
    o[3] = __uint_as_float(v.y & 0xffff0000u);
    o[4] = __uint_as_float(v.z << 16);
    o[5] = __uint_as_float(v.z & 0xffff0000u);
    o[6] = __uint_as_float(v.w << 16);
    o[7] = __uint_as_float(v.w & 0xffff0000u);
}

static __device__ __forceinline__ void acc8(float* acc, uint4 v) {
    float t[8];
    unpack8(t, v);
    #pragma unroll
    for (int i = 0; i < 8; ++i) acc[i] += t[i];
}

// 8 gathers from one packed csr vector (indices s0..s7), accumulate.
static __device__ __forceinline__ void gath8(float* acc, const unsigned short* __restrict__ ps,
                                             u32x4 c, int lane) {
    unsigned s0 = c[0] & 0xffffu, s1 = c[0] >> 16;
    unsigned s2 = c[1] & 0xffffu, s3 = c[1] >> 16;
    unsigned s4 = c[2] & 0xffffu, s5 = c[2] >> 16;
    unsigned s6 = c[3] & 0xffffu, s7 = c[3] >> 16;
    acc8(acc, *(const uint4*)&ps[(size_t)s0 * 32 + lane * 8]);
    acc8(acc, *(const uint4*)&ps[(size_t)s1 * 32 + lane * 8]);
    acc8(acc, *(const uint4*)&ps[(size_t)s2 * 32 + lane * 8]);
    acc8(acc, *(const uint4*)&ps[(size_t)s3 * 32 + lane * 8]);
    acc8(acc, *(const uint4*)&ps[(size_t)s4 * 32 + lane * 8]);
    acc8(acc, *(const uint4*)&ps[(size_t)s5 * 32 + lane * 8]);
    acc8(acc, *(const uint4*)&ps[(size_t)s6 * 32 + lane * 8]);
    acc8(acc, *(const uint4*)&ps[(size_t)s7 * 32 + lane * 8]);
}

// 16 gathers (2 csr vectors): issue ALL loads into registers first, then
// accumulate. Guarantees 16 outstanding row-loads per 4-lane group.
static __device__ __forceinline__ void gath16(float* acc, const unsigned short* __restrict__ ps,
                                              u32x4 c0, u32x4 c1, int lane) {
    unsigned s[16];
    s[0] = c0[0] & 0xffffu;  s[1] = c0[0] >> 16;
    s[2] = c0[1] & 0xffffu;  s[3] = c0[1] >> 16;
    s[4] = c0[2] & 0xffffu;  s[5] = c0[2] >> 16;
    s[6] = c0[3] & 0xffffu;  s[7] = c0[3] >> 16;
    s[8] = c1[0] & 0xffffu;  s[9] = c1[0] >> 16;
    s[10] = c1[1] & 0xffffu; s[11] = c1[1] >> 16;
    s[12] = c1[2] & 0xffffu; s[13] = c1[2] >> 16;
    s[14] = c1[3] & 0xffffu; s[15] = c1[3] >> 16;
    uint4 v[16];
    #pragma unroll
    for (int i = 0; i < 16; ++i)
        v[i] = *(const uint4*)&ps[(size_t)s[i] * 32 + lane * 8];
    #pragma unroll
    for (int i = 0; i < 16; ++i) acc8(acc, v[i]);
}

// ---------------------------------------------------------------------------
// D1: fused cast (x->bf16, W->bf16) + CSR part1 + zero-row init for p1/p2.
__global__ __launch_bounds__(THREADS)
void fused_cast_p1(const float* __restrict__ x, const float* __restrict__ wa,
                   const float* __restrict__ wb, const float* __restrict__ wc,
                   const float* __restrict__ wd, unsigned short* __restrict__ xb,
                   unsigned short* __restrict__ Wb, int nx4,
                   const int* __restrict__ src, const int* __restrict__ dst,
                   unsigned int* __restrict__ pairs, unsigned int* __restrict__ counts,
                   int E, int chunk, int NB,
                   unsigned short* __restrict__ p1z, unsigned short* __restrict__ p2z, int Nn) {
    __shared__ int lh[THREADS], lsc[THREADS], lpos[THREADS];
    __shared__ unsigned int stage[3328];
    int t = threadIdx.x;
    if (blockIdx.x < NBLK1) {
        int e0 = blockIdx.x * chunk, e1 = min(E, e0 + chunk);
        lh[t] = 0;
        __syncthreads();
        for (int e = e0 + t; e < e1; e += THREADS) atomicAdd(&lh[dst[e] >> 8], 1);
        __syncthreads();
        int v = lh[t];
        lsc[t] = v;
        __syncthreads();
        for (int off = 1; off < THREADS; off <<= 1) {
            int tv = (t >= off) ? lsc[t - off] : 0;
            __syncthreads();
            lsc[t] += tv;
            __syncthreads();
        }
        int base = lsc[t] - v;
        lpos[t] = base;
        __syncthreads();
        for (int e = e0 + t; e < e1; e += THREADS) {
            int dd = dst[e];
            int p = atomicAdd(&lpos[dd >> 8], 1);
            stage[p] = (unsigned int)src[e] | ((unsigned int)(dd & 255) << 16);
        }
        __syncthreads();
        int n = e1 - e0;
        for (int i = t; i < n; i += THREADS) pairs[e0 + i] = stage[i];
        if (t < NB)
            counts[(size_t)blockIdx.x * 256 + t] = ((unsigned int)base << 16) | (unsigned int)v;
        return;
    }
    // zero-row init: p1 has 4 slabs of stride (N+1)*32, p2 has 2
    if (blockIdx.x == NBLK1 && t < 192) {
        int wi = t & 31;
        size_t Np32 = (size_t)(Nn + 1) * 32;
        if (t < 128) p1z[(size_t)(t >> 5) * Np32 + (size_t)Nn * 32 + wi] = 0;
        else         p2z[(size_t)((t - 128) >> 5) * Np32 + (size_t)Nn * 32 + wi] = 0;
    }
    int i = (blockIdx.x - NBLK1) * THREADS + t;
    if (i < nx4) {
        float4 v = ((const float4*)x)[i];
        ushort4 u;
        u.x = f2bf(v.x); u.y = f2bf(v.y); u.z = f2bf(v.z); u.w = f2bf(v.w);
        ((ushort4*)xb)[i] = u;
        return;
    }
    int j = i - nx4;
    if (j >= 49152) return;
    float v;
    if (j < 16384) v = wa[j];
    else if (j < 32768) v = wb[j - 16384];
    else if (j < 40960) v = wc[j - 32768];
    else v = wd[j - 40960];
    Wb[j] = f2bf(v);
}

// ---------------------------------------------------------------------------
// MFMA bf16 GEMM body (R9-proven). pOut tables (gathered later) are padded:
// slab stride (M+1)*32 with row M = zeros. rOut tables unpadded (M*32).
template<int NOUT, bool ASLAB>
static __device__ __forceinline__
void gemm_body(const unsigned short* __restrict__ A, const unsigned short* __restrict__ W0,
               const unsigned short* __restrict__ W1, const float* __restrict__ biasR,
               unsigned short* __restrict__ pOut, unsigned short* __restrict__ rOut,
               int M, int job, int xt) {
    constexpr int CT = 4;
    int outSel, chalf;
    if (NOUT == 128) { outSel = job >> 1; chalf = job & 1; }
    else             { outSel = job;      chalf = 0; }
    const unsigned short* W = (outSel ? W1 : W0) + chalf * 64 * 128;

    const int wv = threadIdx.x >> 6, ln = threadIdx.x & 63;
    const int bl = ln & 15, quad = ln >> 4;
    const int mt = xt * 4 + wv;
    const size_t M32 = (size_t)M * 32;
    const size_t Mp32 = (size_t)(M + 1) * 32;

    ABfrag Bf[CT][4];
    #pragma unroll
    for (int ct = 0; ct < CT; ++ct)
        #pragma unroll
        for (int ks = 0; ks < 4; ++ks)
            Bf[ct][ks].q = *(const uint4*)&W[(size_t)(ct * 16 + bl) * 128 + ks * 32 + quad * 8];

    if (mt * 16 >= M) return;
    const int m0 = mt * 16;
    const int arow = m0 + bl;

    floatx4 acc[CT];
    #pragma unroll
    for (int ct = 0; ct < CT; ++ct) acc[ct] = (floatx4){0.f, 0.f, 0.f, 0.f};

    #pragma unroll
    for (int ks = 0; ks < 4; ++ks) {
        ABfrag Af;
        if (ASLAB) Af.q = *(const uint4*)&A[(size_t)ks * M32 + (size_t)arow * 32 + quad * 8];
        else       Af.q = *(const uint4*)&A[(size_t)arow * 128 + ks * 32 + quad * 8];
        #pragma unroll
        for (int ct = 0; ct < CT; ++ct)
            acc[ct] = __builtin_amdgcn_mfma_f32_16x16x32_bf16(Af.v, Bf[ct][ks].v, acc[ct], 0, 0, 0);
    }

    unsigned short* outp = outSel ? rOut : pOut;
    const size_t ostride = outSel ? M32 : Mp32;
    #pragma unroll
    for (int ct = 0; ct < CT; ++ct) {
        int col = chalf * 64 + ct * 16 + bl;
        int slab = col >> 5, wi = col & 31;
        size_t sbase = (size_t)slab * ostride;
        float bv = outSel ? biasR[col] : 0.f;
        #pragma unroll
        for (int i = 0; i < 4; ++i) {
            int row = m0 + quad * 4 + i;
            outp[sbase + (size_t)row * 32 + wi] = f2bf(acc[ct][i] + bv);
        }
    }
}

// ---------------------------------------------------------------------------
// D2: fused layer-1 GEMM + flat-index CSR finalize.
// grid (gemmBlocks, 5): y>=1 -> gemm job y-1; y==0 && x<NB -> finalize.
__global__ __launch_bounds__(THREADS)
void gemm128_csr(const unsigned short* __restrict__ A, const unsigned short* __restrict__ W0,
                 const unsigned short* __restrict__ W1, const float* __restrict__ biasR,
                 unsigned short* __restrict__ pOut, unsigned short* __restrict__ rOut, int M,
                 const unsigned int* __restrict__ pairs, const unsigned int* __restrict__ counts,
                 int* __restrict__ rowptr, unsigned short* __restrict__ degs,
                 unsigned short* __restrict__ csr, int N, int E, int NB, int chunk) {
    __shared__ int runsrc[NBLK1];
    __shared__ int runbase[NBLK1 + 1];
    __shared__ int lhist[THREADS], lscan[THREADS], loff[THREADS];

    if (blockIdx.y != 0) {
        gemm_body<128, false>(A, W0, W1, biasR, pOut, rOut, M, blockIdx.y - 1, blockIdx.x);
        return;
    }
    int b = blockIdx.x, t = threadIdx.x;
    if (b >= NB) return;

    // per-run {length, source offset} from counts; scan lengths -> runbase
    unsigned int pc0 = counts[(size_t)t * 256 + b];
    unsigned int pc1 = counts[(size_t)(t + 256) * 256 + b];
    int c0 = (int)(pc0 & 0xffffu), c1 = (int)(pc1 & 0xffffu);
    runsrc[t] = t * chunk + (int)(pc0 >> 16);
    runsrc[t + 256] = (t + 256) * chunk + (int)(pc1 >> 16);
    lscan[t] = c0;
    __syncthreads();
    for (int off = 1; off < THREADS; off <<= 1) {
        int xx = (t >= off) ? lscan[t - off] : 0;
        __syncthreads();
        lscan[t] += xx;
        __syncthreads();
    }
    runbase[t] = lscan[t] - c0;
    int S0 = lscan[THREADS - 1];
    __syncthreads();
    lscan[t] = c1;
    __syncthreads();
    for (int off = 1; off < THREADS; off <<= 1) {
        int xx = (t >= off) ? lscan[t - off] : 0;
        __syncthreads();
        lscan[t] += xx;
        __syncthreads();
    }
    runbase[256 + t] = S0 + lscan[t] - c1;
    if (t == THREADS - 1) runbase[512] = S0 + lscan[t];
    lhist[t] = 0;
    __syncthreads();
    int sz = runbase[512];

    // Pass A: flat-index histogram. Each element independent: 9-step LDS
    // binary search for its run, then one global load + one LDS atomic.
    for (int i0 = t; i0 < sz; i0 += 4 * THREADS) {
        unsigned pv[4];
        int ok[4];
        #pragma unroll
        for (int k = 0; k < 4; ++k) {
            int i = i0 + k * THREADS;
            ok[k] = (i < sz);
            int idx = ok[k] ? i : (sz - 1);
            int lo = 0, hi = NBLK1;
            #pragma unroll
            for (int s = 0; s < 9; ++s) {
                int mid = (lo + hi) >> 1;
                bool c = runbase[mid] <= idx;
                lo = c ? mid : lo;
                hi = c ? hi : mid;
            }
            pv[k] = pairs[runsrc[lo] + (idx - runbase[lo])];
        }
        #pragma unroll
        for (int k = 0; k < 4; ++k)
            if (ok[k]) atomicAdd(&lhist[(pv[k] >> 16) & 255], 1);
    }
    __syncthreads();

    // padded (8-aligned) counts -> scan -> rowptr / degs / loff / sentinel pads
    int v = lhist[t];
    int pcv = (v + 7) & ~7;
    lscan[t] = pcv;
    __syncthreads();
    for (int off = 1; off < THREADS; off <<= 1) {
        int xx = (t >= off) ? lscan[t - off] : 0;
        __syncthreads();
        lscan[t] += xx;
        __syncthreads();
    }
    int rel = lscan[t] - pcv;
    int base = b * CSTRIDE + rel;
    int id = (b << 8) + t;
    if (id < N) {
        rowptr[id] = base;
        degs[id] = (unsigned short)v;
    }
    loff[t] = base;
    for (int i = v; i < pcv; ++i) csr[base + i] = (unsigned short)N;  // sentinel -> zero row
    __syncthreads();

    // Pass B: flat-index scatter (pairs L2-warm from pass A).
    for (int i0 = t; i0 < sz; i0 += 4 * THREADS) {
        unsigned pv[4];
        int ok[4];
        #pragma unroll
        for (int k = 0; k < 4; ++k) {
            int i = i0 + k * THREADS;
            ok[k] = (i < sz);
            int idx = ok[k] ? i : (sz - 1);
            int lo = 0, hi = NBLK1;
            #pragma unroll
            for (int s = 0; s < 9; ++s) {
                int mid = (lo + hi) >> 1;
                bool c = runbase[mid] <= idx;
                lo = c ? mid : lo;
                hi = c ? hi : mid;
            }
            pv[k] = pairs[runsrc[lo] + (idx - runbase[lo])];
        }
        #pragma unroll
        for (int k = 0; k < 4; ++k)
            if (ok[k]) {
                int pos = atomicAdd(&loff[(pv[k] >> 16) & 255], 1);
                csr[pos] = (unsigned short)(pv[k] & 0xffffu);
            }
    }
}

// D4: layer-2 GEMM (A = h bf16 slab-major unpadded, p2 out padded).
__global__ __launch_bounds__(THREADS)
void gemm64(const unsigned short* __restrict__ A, const unsigned short* __restrict__ W0,
            const unsigned short* __restrict__ W1, const float* __restrict__ b2,
            unsigned short* __restrict__ p2, unsigned short* __restrict__ r2, int M) {
    gemm_body<64, true>(A, W0, W1, b2, p2, r2, M, blockIdx.y, blockIdx.x);
}

// ---------------------------------------------------------------------------
// D3: gather layer 1. 64-node blocks, 1 node per 4-lane group, sentinel-
// padded uniform loop unrolled x2 (gath16: 16 loads in flight).
// XCD-pinned: slab = (b&7)>>1 (XCD pair/slab).
__global__ __launch_bounds__(THREADS)
void gather_h(const unsigned short* __restrict__ p1, const int* __restrict__ rowptr,
              const unsigned short* __restrict__ degs, const unsigned short* __restrict__ csr,
              const unsigned short* __restrict__ r1, unsigned short* __restrict__ h,
              int N, int nodeBlocks) {
    __shared__ int sdeg[64], perm[64];
    const size_t N32 = (size_t)N * 32;
    const size_t Np32 = (size_t)(N + 1) * 32;
    int b = blockIdx.x;
    int slab = (b & 7) >> 1;
    int nb = ((b >> 3) << 1) | (b & 1);
    if (nb >= nodeBlocks) return;
    int g0 = nb * 64;
    int t = threadIdx.x;
    if (t < 64) {
        int g = g0 + t;
        sdeg[t] = (g < N) ? (int)degs[g] : -1;
    }
    __syncthreads();
    if (t < 64) {
        int d = sdeg[t], r = 0;
        #pragma unroll 8
        for (int j = 0; j < 64; ++j) {
            int dj = sdeg[j];
            r += (dj < d) || (dj == d && j < t);
        }
        perm[r] = t;
    }
    __syncthreads();
    int g = g0 + perm[t >> 2];
    if (g >= N) return;
    int lane = t & 3;
    const unsigned short* ps = p1 + (size_t)slab * Np32;
    int start = rowptr[g];
    int deg = degs[g];
    int niter = (deg + 7) >> 3;
    V4 rv;
    rv.w = __builtin_nontemporal_load((const u32x4*)(r1 + slab * N32 + (size_t)g * 32 + lane * 8));
    float acc[8] = {0.f, 0.f, 0.f, 0.f, 0.f, 0.f, 0.f, 0.f};
    const unsigned short* cp = csr + start;   // 16B aligned by construction
    int nit2 = niter & ~1;
    int it = 0;
    for (; it < nit2; it += 2) {
        u32x4 c0 = __builtin_nontemporal_load((const u32x4*)(cp + it * 8));
        u32x4 c1 = __builtin_nontemporal_load((const u32x4*)(cp + it * 8 + 8));
        gath16(acc, ps, c0, c1, lane);
    }
    if (it < niter) {
        u32x4 c = __builtin_nontemporal_load((const u32x4*)(cp + it * 8));
        gath8(acc, ps, c, lane);
    }
    float rc = 1.0f / fmaxf((float)deg, 1.0f);
    float rr[8];
    unpack8(rr, rv.q);
    float o[8];
    #pragma unroll
    for (int i = 0; i < 8; ++i) o[i] = fmaxf(acc[i] * rc + rr[i], 0.f);
    u32x4 u;
    u[0] = (unsigned)f2bf(o[0]) | ((unsigned)f2bf(o[1]) << 16);
    u[1] = (unsigned)f2bf(o[2]) | ((unsigned)f2bf(o[3]) << 16);
    u[2] = (unsigned)f2bf(o[4]) | ((unsigned)f2bf(o[5]) << 16);
    u[3] = (unsigned)f2bf(o[6]) | ((unsigned)f2bf(o[7]) << 16);
    __builtin_nontemporal_store(u, (u32x4*)(h + slab * N32 + (size_t)g * 32 + lane * 8));
}

// D5: gather layer 2 (final). 64-node blocks, 1 node per group, unroll x2.
// XCD-pinned: slab = (b&7)>>2 (XCD quad per slab).
__global__ __launch_bounds__(THREADS)
void gather_out(const unsigned short* __restrict__ p2, const int* __restrict__ rowptr,
                const unsigned short* __restrict__ degs, const unsigned short* __restrict__ csr,
                const unsigned short* __restrict__ r2, float* __restrict__ out,
                int N, int nodeBlocks) {
    __shared__ int sdeg[64], perm[64];
    const size_t N32 = (size_t)N * 32;
    const size_t Np32 = (size_t)(N + 1) * 32;
    int b = blockIdx.x;
    int slab = (b & 7) >> 2;
    int nb = ((b >> 3) << 2) | (b & 3);
    if (nb >= nodeBlocks) return;
    int g0 = nb * 64;
    int t = threadIdx.x;
    if (t < 64) {
        int g = g0 + t;
        sdeg[t] = (g < N) ? (int)degs[g] : -1;
    }
    __syncthreads();
    if (t < 64) {
        int d = sdeg[t], r = 0;
        #pragma unroll 8
        for (int j = 0; j < 64; ++j) {
            int dj = sdeg[j];
            r += (dj < d) || (dj == d && j < t);
        }
        perm[r] = t;
    }
    __syncthreads();
    int g = g0 + perm[t >> 2];
    if (g >= N) return;
    int lane = t & 3;
    const unsigned short* ps = p2 + (size_t)slab * Np32;
    int start = rowptr[g];
    int deg = degs[g];
    int niter = (deg + 7) >> 3;
    V4 rv;
    rv.w = __builtin_nontemporal_load((const u32x4*)(r2 + slab * N32 + (size_t)g * 32 + lane * 8));
    float acc[8] = {0.f, 0.f, 0.f, 0.f, 0.f, 0.f, 0.f, 0.f};
    const unsigned short* cp = csr + start;
    int nit2 = niter & ~1;
    int it = 0;
    for (; it < nit2; it += 2) {
        u32x4 c0 = __builtin_nontemporal_load((const u32x4*)(cp + it * 8));
        u32x4 c1 = __builtin_nontemporal_load((const u32x4*)(cp + it * 8 + 8));
        gath16(acc, ps, c0, c1, lane);
    }
    if (it < niter) {
        u32x4 c = __builtin_nontemporal_load((const u32x4*)(cp + it * 8));
        gath8(acc, ps, c, lane);
    }
    float rc = 1.0f / fmaxf((float)deg, 1.0f);
    float rr[8];
    unpack8(rr, rv.q);
    f32x4 o0, o1;
    #pragma unroll
    for (int i = 0; i < 4; ++i) o0[i] = acc[i] * rc + rr[i];
    #pragma unroll
    for (int i = 0; i < 4; ++i) o1[i] = acc[4 + i] * rc + rr[4 + i];
    f32x4* o4 = (f32x4*)(out + (size_t)g * 64 + slab * 32 + lane * 8);
    __builtin_nontemporal_store(o0, o4);
    __builtin_nontemporal_store(o1, o4 + 1);
}

// ---------------------------------------------------------------------------
extern "C" void kernel_launch(void* const* d_in, const int* in_sizes, int n_in,
                              void* d_out, int out_size, void* d_ws, size_t ws_size,
                              hipStream_t stream) {
    const float* x   = (const float*)d_in[0];
    const int* edges = (const int*)d_in[1];
    const float* Wl1 = (const float*)d_in[2];
    const float* Wr1 = (const float*)d_in[3];
    const float* b1  = (const float*)d_in[4];
    const float* Wl2 = (const float*)d_in[5];
    const float* Wr2 = (const float*)d_in[6];
    const float* b2  = (const float*)d_in[7];
    float* out = (float*)d_out;

    const int N = in_sizes[0] / 128;     // 50000 (< 65536)
    const int E = in_sizes[1] / 2;       // 1600000
    const int NB = (N + 255) >> 8;       // 196
    const int chunk = (E + NBLK1 - 1) / NBLK1;   // 3125
    const int* src = edges;
    const int* dstv = edges + E;

    // Workspace (slab-major tables; p1/p2 padded with zero row N)
    char* wsp = (char*)d_ws;
    unsigned short* p1  = (unsigned short*)wsp;  wsp += (size_t)(N + 1) * 128 * 2;
    unsigned short* r1  = (unsigned short*)wsp;  wsp += (size_t)N * 128 * 2;
    unsigned short* h   = (unsigned short*)wsp;  wsp += (size_t)N * 128 * 2;
    unsigned short* p2  = (unsigned short*)wsp;  wsp += (size_t)(N + 1) * 64 * 2;
    unsigned short* r2  = (unsigned short*)wsp;  wsp += (size_t)N * 64 * 2;
    unsigned short* xb  = (unsigned short*)wsp;  wsp += (size_t)N * 128 * 2;
    unsigned int* pairs = (unsigned int*)wsp;    wsp += (size_t)E * 4;
    unsigned short* csr = (unsigned short*)wsp;  wsp += (size_t)NB * CSTRIDE * 2;  // 4.8 MB
    unsigned short* Wb  = (unsigned short*)wsp;  wsp += (size_t)49152 * 2;
    unsigned int* counts= (unsigned int*)wsp;    wsp += (size_t)NBLK1 * 256 * 4;
    int* rowptr         = (int*)wsp;             wsp += (size_t)(N + 1) * 4;
    unsigned short* degs= (unsigned short*)wsp;  wsp += (size_t)((N + 1) & ~1) * 2;

    unsigned short* Wl1b = Wb;
    unsigned short* Wr1b = Wb + 16384;
    unsigned short* Wl2b = Wb + 32768;
    unsigned short* Wr2b = Wb + 40960;

    const int nx4 = N * 128 / 4;
    const int castBlocks = (nx4 + 49152 + THREADS - 1) / THREADS;
    const int MT = (N + 15) / 16;                 // 3125
    const int gemmBlocks = (MT + 3) / 4;          // 782
    const int nodeBlocks = (N + 63) / 64;         // 782

    // D1: fused cast + CSR part1 + zero-row init
    fused_cast_p1<<<NBLK1 + castBlocks, THREADS, 0, stream>>>(
        x, Wl1, Wr1, Wl2, Wr2, xb, Wb, nx4, src, dstv, pairs, counts, E, chunk, NB,
        p1, p2, N);

    // D2: layer-1 GEMM (4 jobs) + flat-index CSR finalize (y==0)
    gemm128_csr<<<dim3(gemmBlocks, 5), THREADS, 0, stream>>>(
        xb, Wl1b, Wr1b, b1, p1, r1, N,
        pairs, counts, rowptr, degs, csr, N, E, NB, chunk);

    // D3: gather layer 1 (4 slabs, XCD-pinned: 2 XCDs per slab)
    gather_h<<<8 * ((nodeBlocks + 1) / 2), THREADS, 0, stream>>>(
        p1, rowptr, degs, csr, r1, h, N, nodeBlocks);

    // D4: layer-2 GEMM
    gemm64<<<dim3(gemmBlocks, 2), THREADS, 0, stream>>>(h, Wl2b, Wr2b, b2, p2, r2, N);

    // D5: gather layer 2 -> final output (2 slabs, XCD-pinned: 4 XCDs per slab)
    gather_out<<<8 * ((nodeBlocks + 3) / 4), THREADS, 0, stream>>>(
        p2, rowptr, degs, csr, r2, out, N, nodeBlocks);
}

// Round 7
// 227.708 us; speedup vs baseline: 1.3294x; 1.0996x over previous
//
#include <hip/hip_runtime.h>
#include <hip/hip_bf16.h>

// GraphSAGE 2-layer forward.
// R21 = R20 + fp8 aggregate tables (MSHR-wall fix):
//  - R20 falsified the MLP hypothesis: 16-deep in-flight bought 6%. Measured
//    line rate 0.19 lines/cy/CU == MSHR_count/latency -> the gather is at the
//    per-CU outstanding-miss throughput wall. Only lever: fewer 64B lines.
//  - p1/p2 (the GATHERED tables) become fp8 e4m3 with 64-col rows = exactly
//    one 64B line per row: gather_h lines 6.4M->3.2M, gather_out 3.2M->1.6M.
//    Encode via v_cvt_pk_fp8_f32 in the GEMM epilogue; decode via
//    v_cvt_pk_f32_fp8 in the gather (gfx950 OCP, HW roundtrip-consistent).
//  - Self terms r1/r2 (+bias) and h stay bf16 -> fp8 noise only enters via
//    the mean over ~32 neighbors (~0.5% rel on the agg term).
//  - Gathers: 128-thread / 32-node blocks keep grid ~3128 (R19 TLP lesson).
//    p1: 2 slabs pinned to XCD quads (3.2MB per L2). p2: 1 slab, no pinning.
//  - h keeps [4][N][32] bf16 layout; gemm64 unchanged.

#define THREADS 256
#define GTH 128            // gather block size (32 nodes x 4 lanes)
#define NBLK1 512          // csr part1 blocks (chunk = 3125 <= 3328 stage cap)
#define CSTRIDE 12288      // padded csr entries per 256-node bucket

typedef __bf16 bf16x8 __attribute__((ext_vector_type(8)));
typedef float floatx4 __attribute__((ext_vector_type(4)));
typedef float f32x4 __attribute__((ext_vector_type(4)));
typedef float f32x2 __attribute__((ext_vector_type(2)));
typedef unsigned int u32x4 __attribute__((ext_vector_type(4)));

union ABfrag { bf16x8 v; unsigned short u[8]; uint4 q; };
union V4 { u32x4 w; uint4 q; };

static __device__ __forceinline__ unsigned short f2bf(float f) {
    unsigned int u = __float_as_uint(f);
    u = (u + 0x7fffu + ((u >> 16) & 1u)) >> 16;   // RNE
    return (unsigned short)u;
}

static __device__ __forceinline__ unsigned char f2fp8(float f) {
    int pk = __builtin_amdgcn_cvt_pk_fp8_f32(f, f, 0, false);   // OCP e4m3, RNE+sat
    return (unsigned char)(pk & 0xff);
}

static __device__ __forceinline__ void unpack8(float* o, uint4 v) {
    o[0] = __uint_as_float(v.x << 16);
    o[1] = __uint_as_float(v.x & 0xffff0000u);
    o[2] = __uint_as_float(v.y << 16);
    o[3] = __uint_as_float(v.y & 0xffff0000u);
    o[4] = __uint_as_float(v.z << 16);
    o[5] = __uint_as_float(v.z & 0xffff0000u);
    o[6] = __uint_as_float(v.w << 16);
    o[7] = __uint_as_float(v.w & 0xffff0000u);
}

// decode 16 fp8 (one uint4 = 16 cols) and accumulate into acc[16]
static __device__ __forceinline__ void accf8(float* acc, uint4 v) {
    unsigned w[4] = {v.x, v.y, v.z, v.w};
    #pragma unroll
    for (int j = 0; j < 4; ++j) {
        f32x2 a = __builtin_amdgcn_cvt_pk_f32_fp8(w[j], false);
        f32x2 c = __builtin_amdgcn_cvt_pk_f32_fp8(w[j], true);
        acc[j * 4 + 0] += a[0];
        acc[j * 4 + 1] += a[1];
        acc[j * 4 + 2] += c[0];
        acc[j * 4 + 3] += c[1];
    }
}

// 8 fp8 row-gathers (one 64B line each), all loads issued before any decode.
static __device__ __forceinline__ void gath8f(float* acc, const unsigned char* __restrict__ ps,
                                              u32x4 c, int lane) {
    unsigned s[8];
    s[0] = c[0] & 0xffffu; s[1] = c[0] >> 16;
    s[2] = c[1] & 0xffffu; s[3] = c[1] >> 16;
    s[4] = c[2] & 0xffffu; s[5] = c[2] >> 16;
    s[6] = c[3] & 0xffffu; s[7] = c[3] >> 16;
    uint4 v[8];
    #pragma unroll
    for (int i = 0; i < 8; ++i)
        v[i] = *(const uint4*)(ps + (size_t)s[i] * 64 + lane * 16);
    #pragma unroll
    for (int i = 0; i < 8; ++i) accf8(acc, v[i]);
}

// 16 fp8 row-gathers in flight (2 csr vectors).
static __device__ __forceinline__ void gath16f(float* acc, const unsigned char* __restrict__ ps,
                                               u32x4 c0, u32x4 c1, int lane) {
    unsigned s[16];
    s[0] = c0[0] & 0xffffu;  s[1] = c0[0] >> 16;
    s[2] = c0[1] & 0xffffu;  s[3] = c0[1] >> 16;
    s[4] = c0[2] & 0xffffu;  s[5] = c0[2] >> 16;
    s[6] = c0[3] & 0xffffu;  s[7] = c0[3] >> 16;
    s[8] = c1[0] & 0xffffu;  s[9] = c1[0] >> 16;
    s[10] = c1[1] & 0xffffu; s[11] = c1[1] >> 16;
    s[12] = c1[2] & 0xffffu; s[13] = c1[2] >> 16;
    s[14] = c1[3] & 0xffffu; s[15] = c1[3] >> 16;
    uint4 v[16];
    #pragma unroll
    for (int i = 0; i < 16; ++i)
        v[i] = *(const uint4*)(ps + (size_t)s[i] * 64 + lane * 16);
    #pragma unroll
    for (int i = 0; i < 16; ++i) accf8(acc, v[i]);
}

// ---------------------------------------------------------------------------
// D1: fused cast (x->bf16, W->bf16) + CSR part1 + fp8 zero-row init.
__global__ __launch_bounds__(THREADS)
void fused_cast_p1(const float* __restrict__ x, const float* __restrict__ wa,
                   const float* __restrict__ wb, const float* __restrict__ wc,
                   const float* __restrict__ wd, unsigned short* __restrict__ xb,
                   unsigned short* __restrict__ Wb, int nx4,
                   const int* __restrict__ src, const int* __restrict__ dst,
                   unsigned int* __restrict__ pairs, unsigned int* __restrict__ counts,
                   int E, int chunk, int NB,
                   unsigned char* __restrict__ p1z, unsigned char* __restrict__ p2z, int Nn) {
    __shared__ int lh[THREADS], lsc[THREADS], lpos[THREADS];
    __shared__ unsigned int stage[3328];
    int t = threadIdx.x;
    if (blockIdx.x < NBLK1) {
        int e0 = blockIdx.x * chunk, e1 = min(E, e0 + chunk);
        lh[t] = 0;
        __syncthreads();
        for (int e = e0 + t; e < e1; e += THREADS) atomicAdd(&lh[dst[e] >> 8], 1);
        __syncthreads();
        int v = lh[t];
        lsc[t] = v;
        __syncthreads();
        for (int off = 1; off < THREADS; off <<= 1) {
            int tv = (t >= off) ? lsc[t - off] : 0;
            __syncthreads();
            lsc[t] += tv;
            __syncthreads();
        }
        int base = lsc[t] - v;
        lpos[t] = base;
        __syncthreads();
        for (int e = e0 + t; e < e1; e += THREADS) {
            int dd = dst[e];
            int p = atomicAdd(&lpos[dd >> 8], 1);
            stage[p] = (unsigned int)src[e] | ((unsigned int)(dd & 255) << 16);
        }
        __syncthreads();
        int n = e1 - e0;
        for (int i = t; i < n; i += THREADS) pairs[e0 + i] = stage[i];
        if (t < NB)
            counts[(size_t)blockIdx.x * 256 + t] = ((unsigned int)base << 16) | (unsigned int)v;
        return;
    }
    // fp8 zero-row init: p1 has 2 slabs stride (N+1)*64 B, p2 has 1
    if (blockIdx.x == NBLK1 && t < 192) {
        size_t Np64 = (size_t)(Nn + 1) * 64;
        if (t < 128) p1z[(size_t)(t >> 6) * Np64 + (size_t)Nn * 64 + (t & 63)] = 0;
        else         p2z[(size_t)Nn * 64 + (t - 128)] = 0;
    }
    int i = (blockIdx.x - NBLK1) * THREADS + t;
    if (i < nx4) {
        float4 v = ((const float4*)x)[i];
        ushort4 u;
        u.x = f2bf(v.x); u.y = f2bf(v.y); u.z = f2bf(v.z); u.w = f2bf(v.w);
        ((ushort4*)xb)[i] = u;
        return;
    }
    int j = i - nx4;
    if (j >= 49152) return;
    float v;
    if (j < 16384) v = wa[j];
    else if (j < 32768) v = wb[j - 16384];
    else if (j < 40960) v = wc[j - 32768];
    else v = wd[j - 40960];
    Wb[j] = f2bf(v);
}

// ---------------------------------------------------------------------------
// MFMA bf16 GEMM body. p-outputs (gathered later) are fp8 [slab][(M+1)][64]
// with zero row M; r-outputs stay bf16 slab-major [col>>5][M][32] (+bias).
template<int NOUT, bool ASLAB>
static __device__ __forceinline__
void gemm_body(const unsigned short* __restrict__ A, const unsigned short* __restrict__ W0,
               const unsigned short* __restrict__ W1, const float* __restrict__ biasR,
               unsigned char* __restrict__ pOut, unsigned short* __restrict__ rOut,
               int M, int job, int xt) {
    constexpr int CT = 4;
    int outSel, chalf;
    if (NOUT == 128) { outSel = job >> 1; chalf = job & 1; }
    else             { outSel = job;      chalf = 0; }
    const unsigned short* W = (outSel ? W1 : W0) + chalf * 64 * 128;

    const int wv = threadIdx.x >> 6, ln = threadIdx.x & 63;
    const int bl = ln & 15, quad = ln >> 4;
    const int mt = xt * 4 + wv;
    const size_t M32 = (size_t)M * 32;
    const size_t Mp64 = (size_t)(M + 1) * 64;

    ABfrag Bf[CT][4];
    #pragma unroll
    for (int ct = 0; ct < CT; ++ct)
        #pragma unroll
        for (int ks = 0; ks < 4; ++ks)
            Bf[ct][ks].q = *(const uint4*)&W[(size_t)(ct * 16 + bl) * 128 + ks * 32 + quad * 8];

    if (mt * 16 >= M) return;
    const int m0 = mt * 16;
    const int arow = m0 + bl;

    floatx4 acc[CT];
    #pragma unroll
    for (int ct = 0; ct < CT; ++ct) acc[ct] = (floatx4){0.f, 0.f, 0.f, 0.f};

    #pragma unroll
    for (int ks = 0; ks < 4; ++ks) {
        ABfrag Af;
        if (ASLAB) Af.q = *(const uint4*)&A[(size_t)ks * M32 + (size_t)arow * 32 + quad * 8];
        else       Af.q = *(const uint4*)&A[(size_t)arow * 128 + ks * 32 + quad * 8];
        #pragma unroll
        for (int ct = 0; ct < CT; ++ct)
            acc[ct] = __builtin_amdgcn_mfma_f32_16x16x32_bf16(Af.v, Bf[ct][ks].v, acc[ct], 0, 0, 0);
    }

    if (outSel) {
        // bf16 r-out with bias, slab-major 32-col
        #pragma unroll
        for (int ct = 0; ct < CT; ++ct) {
            int col = chalf * 64 + ct * 16 + bl;
            int slab = col >> 5, wi = col & 31;
            size_t sbase = (size_t)slab * M32;
            float bv = biasR[col];
            #pragma unroll
            for (int i = 0; i < 4; ++i) {
                int row = m0 + quad * 4 + i;
                rOut[sbase + (size_t)row * 32 + wi] = f2bf(acc[ct][i] + bv);
            }
        }
    } else {
        // fp8 p-out, [slab8][(M+1)][64], no bias
        #pragma unroll
        for (int ct = 0; ct < CT; ++ct) {
            int col = chalf * 64 + ct * 16 + bl;
            int slab8 = col >> 6, wi = col & 63;
            unsigned char* pp = pOut + (size_t)slab8 * Mp64;
            #pragma unroll
            for (int i = 0; i < 4; ++i) {
                int row = m0 + quad * 4 + i;
                pp[(size_t)row * 64 + wi] = f2fp8(acc[ct][i]);
            }
        }
    }
}

// ---------------------------------------------------------------------------
// D2: fused layer-1 GEMM + flat-index CSR finalize.
// grid (gemmBlocks, 5): y>=1 -> gemm job y-1; y==0 && x<NB -> finalize.
__global__ __launch_bounds__(THREADS)
void gemm128_csr(const unsigned short* __restrict__ A, const unsigned short* __restrict__ W0,
                 const unsigned short* __restrict__ W1, const float* __restrict__ biasR,
                 unsigned char* __restrict__ pOut, unsigned short* __restrict__ rOut, int M,
                 const unsigned int* __restrict__ pairs, const unsigned int* __restrict__ counts,
                 int* __restrict__ rowptr, unsigned short* __restrict__ degs,
                 unsigned short* __restrict__ csr, int N, int E, int NB, int chunk) {
    __shared__ int runsrc[NBLK1];
    __shared__ int runbase[NBLK1 + 1];
    __shared__ int lhist[THREADS], lscan[THREADS], loff[THREADS];

    if (blockIdx.y != 0) {
        gemm_body<128, false>(A, W0, W1, biasR, pOut, rOut, M, blockIdx.y - 1, blockIdx.x);
        return;
    }
    int b = blockIdx.x, t = threadIdx.x;
    if (b >= NB) return;

    // per-run {length, source offset} from counts; scan lengths -> runbase
    unsigned int pc0 = counts[(size_t)t * 256 + b];
    unsigned int pc1 = counts[(size_t)(t + 256) * 256 + b];
    int c0 = (int)(pc0 & 0xffffu), c1 = (int)(pc1 & 0xffffu);
    runsrc[t] = t * chunk + (int)(pc0 >> 16);
    runsrc[t + 256] = (t + 256) * chunk + (int)(pc1 >> 16);
    lscan[t] = c0;
    __syncthreads();
    for (int off = 1; off < THREADS; off <<= 1) {
        int xx = (t >= off) ? lscan[t - off] : 0;
        __syncthreads();
        lscan[t] += xx;
        __syncthreads();
    }
    runbase[t] = lscan[t] - c0;
    int S0 = lscan[THREADS - 1];
    __syncthreads();
    lscan[t] = c1;
    __syncthreads();
    for (int off = 1; off < THREADS; off <<= 1) {
        int xx = (t >= off) ? lscan[t - off] : 0;
        __syncthreads();
        lscan[t] += xx;
        __syncthreads();
    }
    runbase[256 + t] = S0 + lscan[t] - c1;
    if (t == THREADS - 1) runbase[512] = S0 + lscan[t];
    lhist[t] = 0;
    __syncthreads();
    int sz = runbase[512];

    // Pass A: flat-index histogram (9-step LDS binsearch, x4 unroll for MLP).
    for (int i0 = t; i0 < sz; i0 += 4 * THREADS) {
        unsigned pv[4];
        int ok[4];
        #pragma unroll
        for (int k = 0; k < 4; ++k) {
            int i = i0 + k * THREADS;
            ok[k] = (i < sz);
            int idx = ok[k] ? i : (sz - 1);
            int lo = 0, hi = NBLK1;
            #pragma unroll
            for (int s = 0; s < 9; ++s) {
                int mid = (lo + hi) >> 1;
                bool c = runbase[mid] <= idx;
                lo = c ? mid : lo;
                hi = c ? hi : mid;
            }
            pv[k] = pairs[runsrc[lo] + (idx - runbase[lo])];
        }
        #pragma unroll
        for (int k = 0; k < 4; ++k)
            if (ok[k]) atomicAdd(&lhist[(pv[k] >> 16) & 255], 1);
    }
    __syncthreads();

    // padded (8-aligned) counts -> scan -> rowptr / degs / loff / sentinel pads
    int v = lhist[t];
    int pcv = (v + 7) & ~7;
    lscan[t] = pcv;
    __syncthreads();
    for (int off = 1; off < THREADS; off <<= 1) {
        int xx = (t >= off) ? lscan[t - off] : 0;
        __syncthreads();
        lscan[t] += xx;
        __syncthreads();
    }
    int rel = lscan[t] - pcv;
    int base = b * CSTRIDE + rel;
    int id = (b << 8) + t;
    if (id < N) {
        rowptr[id] = base;
        degs[id] = (unsigned short)v;
    }
    loff[t] = base;
    for (int i = v; i < pcv; ++i) csr[base + i] = (unsigned short)N;  // sentinel -> zero row
    __syncthreads();

    // Pass B: flat-index scatter (pairs L2-warm from pass A).
    for (int i0 = t; i0 < sz; i0 += 4 * THREADS) {
        unsigned pv[4];
        int ok[4];
        #pragma unroll
        for (int k = 0; k < 4; ++k) {
            int i = i0 + k * THREADS;
            ok[k] = (i < sz);
            int idx = ok[k] ? i : (sz - 1);
            int lo = 0, hi = NBLK1;
            #pragma unroll
            for (int s = 0; s < 9; ++s) {
                int mid = (lo + hi) >> 1;
                bool c = runbase[mid] <= idx;
                lo = c ? mid : lo;
                hi = c ? hi : mid;
            }
            pv[k] = pairs[runsrc[lo] + (idx - runbase[lo])];
        }
        #pragma unroll
        for (int k = 0; k < 4; ++k)
            if (ok[k]) {
                int pos = atomicAdd(&loff[(pv[k] >> 16) & 255], 1);
                csr[pos] = (unsigned short)(pv[k] & 0xffffu);
            }
    }
}

// D4: layer-2 GEMM (A = h bf16 slab-major; p2 fp8, r2 bf16).
__global__ __launch_bounds__(THREADS)
void gemm64(const unsigned short* __restrict__ A, const unsigned short* __restrict__ W0,
            const unsigned short* __restrict__ W1, const float* __restrict__ b2,
            unsigned char* __restrict__ p2, unsigned short* __restrict__ r2, int M) {
    gemm_body<64, true>(A, W0, W1, b2, p2, r2, M, blockIdx.y, blockIdx.x);
}

// ---------------------------------------------------------------------------
// D3: gather layer 1 (fp8). 32-node blocks of 128 threads; 4 lanes/node;
// p1 = 2 fp8 slabs of 64 cols (one 64B line per row-gather), pinned to XCD
// quads. h out / r1 in stay bf16 [4][N][32].
__global__ __launch_bounds__(GTH)
void gather_h(const unsigned char* __restrict__ p1, const int* __restrict__ rowptr,
              const unsigned short* __restrict__ degs, const unsigned short* __restrict__ csr,
              const unsigned short* __restrict__ r1, unsigned short* __restrict__ h,
              int N, int nodeBlocks) {
    __shared__ int sdeg[32], perm[32];
    const size_t N32 = (size_t)N * 32;
    const size_t Np64 = (size_t)(N + 1) * 64;
    int b = blockIdx.x;
    int slab = (b & 7) >> 2;                    // 2 slabs, one XCD quad each
    int nb = ((b >> 3) << 2) | (b & 3);
    if (nb >= nodeBlocks) return;
    int g0 = nb * 32;
    int t = threadIdx.x;
    if (t < 32) {
        int g = g0 + t;
        sdeg[t] = (g < N) ? (int)degs[g] : -1;
    }
    __syncthreads();
    if (t < 32) {
        int d = sdeg[t], r = 0;
        #pragma unroll 8
        for (int j = 0; j < 32; ++j) {
            int dj = sdeg[j];
            r += (dj < d) || (dj == d && j < t);
        }
        perm[r] = t;
    }
    __syncthreads();
    int g = g0 + perm[t >> 2];
    if (g >= N) return;
    int lane = t & 3;
    const unsigned char* ps = p1 + (size_t)slab * Np64;
    int start = rowptr[g];
    int deg = degs[g];
    int niter = (deg + 7) >> 3;
    // bf16 self-term: global col = slab*64 + lane*16 + i
    int ks = slab * 2 + (lane >> 1);
    int co = (lane & 1) * 16;
    const unsigned short* rp = r1 + (size_t)ks * N32 + (size_t)g * 32 + co;
    V4 rv0, rv1;
    rv0.w = __builtin_nontemporal_load((const u32x4*)rp);
    rv1.w = __builtin_nontemporal_load((const u32x4*)(rp + 8));
    float acc[16];
    #pragma unroll
    for (int i = 0; i < 16; ++i) acc[i] = 0.f;
    const unsigned short* cp = csr + start;   // 16B aligned by construction
    int nit2 = niter & ~1;
    int it = 0;
    for (; it < nit2; it += 2) {
        u32x4 c0 = __builtin_nontemporal_load((const u32x4*)(cp + it * 8));
        u32x4 c1 = __builtin_nontemporal_load((const u32x4*)(cp + it * 8 + 8));
        gath16f(acc, ps, c0, c1, lane);
    }
    if (it < niter) {
        u32x4 c = __builtin_nontemporal_load((const u32x4*)(cp + it * 8));
        gath8f(acc, ps, c, lane);
    }
    float rc = 1.0f / fmaxf((float)deg, 1.0f);
    float rr[16];
    unpack8(rr, rv0.q);
    unpack8(rr + 8, rv1.q);
    float o[16];
    #pragma unroll
    for (int i = 0; i < 16; ++i) o[i] = fmaxf(acc[i] * rc + rr[i], 0.f);
    u32x4 u0, u1;
    #pragma unroll
    for (int k = 0; k < 4; ++k) {
        u0[k] = (unsigned)f2bf(o[2 * k]) | ((unsigned)f2bf(o[2 * k + 1]) << 16);
        u1[k] = (unsigned)f2bf(o[8 + 2 * k]) | ((unsigned)f2bf(o[8 + 2 * k + 1]) << 16);
    }
    unsigned short* hp = h + (size_t)ks * N32 + (size_t)g * 32 + co;
    __builtin_nontemporal_store(u0, (u32x4*)hp);
    __builtin_nontemporal_store(u1, (u32x4*)(hp + 8));
}

// D5: gather layer 2 (fp8, final). p2 = 1 fp8 slab of 64 cols; r2 bf16
// [2][N][32]; out f32 [N][64].
__global__ __launch_bounds__(GTH)
void gather_out(const unsigned char* __restrict__ p2, const int* __restrict__ rowptr,
                const unsigned short* __restrict__ degs, const unsigned short* __restrict__ csr,
                const unsigned short* __restrict__ r2, float* __restrict__ out,
                int N, int nodeBlocks) {
    __shared__ int sdeg[32], perm[32];
    const size_t N32 = (size_t)N * 32;
    int b = blockIdx.x;
    if (b >= nodeBlocks) return;
    int g0 = b * 32;
    int t = threadIdx.x;
    if (t < 32) {
        int g = g0 + t;
        sdeg[t] = (g < N) ? (int)degs[g] : -1;
    }
    __syncthreads();
    if (t < 32) {
        int d = sdeg[t], r = 0;
        #pragma unroll 8
        for (int j = 0; j < 32; ++j) {
            int dj = sdeg[j];
            r += (dj < d) || (dj == d && j < t);
        }
        perm[r] = t;
    }
    __syncthreads();
    int g = g0 + perm[t >> 2];
    if (g >= N) return;
    int lane = t & 3;
    int start = rowptr[g];
    int deg = degs[g];
    int niter = (deg + 7) >> 3;
    int ks = lane >> 1;
    int co = (lane & 1) * 16;
    const unsigned short* rp = r2 + (size_t)ks * N32 + (size_t)g * 32 + co;
    V4 rv0, rv1;
    rv0.w = __builtin_nontemporal_load((const u32x4*)rp);
    rv1.w = __builtin_nontemporal_load((const u32x4*)(rp + 8));
    float acc[16];
    #pragma unroll
    for (int i = 0; i < 16; ++i) acc[i] = 0.f;
    const unsigned short* cp = csr + start;
    int nit2 = niter & ~1;
    int it = 0;
    for (; it < nit2; it += 2) {
        u32x4 c0 = __builtin_nontemporal_load((const u32x4*)(cp + it * 8));
        u32x4 c1 = __builtin_nontemporal_load((const u32x4*)(cp + it * 8 + 8));
        gath16f(acc, p2, c0, c1, lane);
    }
    if (it < niter) {
        u32x4 c = __builtin_nontemporal_load((const u32x4*)(cp + it * 8));
        gath8f(acc, p2, c, lane);
    }
    float rc = 1.0f / fmaxf((float)deg, 1.0f);
    float rr[16];
    unpack8(rr, rv0.q);
    unpack8(rr + 8, rv1.q);
    float* op = out + (size_t)g * 64 + lane * 16;
    #pragma unroll
    for (int q = 0; q < 4; ++q) {
        f32x4 o;
        #pragma unroll
        for (int k = 0; k < 4; ++k) o[k] = acc[q * 4 + k] * rc + rr[q * 4 + k];
        __builtin_nontemporal_store(o, (f32x4*)(op + q * 4));
    }
}

// ---------------------------------------------------------------------------
extern "C" void kernel_launch(void* const* d_in, const int* in_sizes, int n_in,
                              void* d_out, int out_size, void* d_ws, size_t ws_size,
                              hipStream_t stream) {
    const float* x   = (const float*)d_in[0];
    const int* edges = (const int*)d_in[1];
    const float* Wl1 = (const float*)d_in[2];
    const float* Wr1 = (const float*)d_in[3];
    const float* b1  = (const float*)d_in[4];
    const float* Wl2 = (const float*)d_in[5];
    const float* Wr2 = (const float*)d_in[6];
    const float* b2  = (const float*)d_in[7];
    float* out = (float*)d_out;

    const int N = in_sizes[0] / 128;     // 50000 (< 65536)
    const int E = in_sizes[1] / 2;       // 1600000
    const int NB = (N + 255) >> 8;       // 196
    const int chunk = (E + NBLK1 - 1) / NBLK1;   // 3125
    const int* src = edges;
    const int* dstv = edges + E;

    // Workspace: fp8 p-tables (zero row N), bf16 r/h tables
    char* wsp = (char*)d_ws;
    unsigned char* p1   = (unsigned char*)wsp;   wsp += (size_t)(N + 1) * 128;    //  6.4 MB (2 slabs x 64B)
    unsigned short* r1  = (unsigned short*)wsp;  wsp += (size_t)N * 128 * 2;      // 12.8 MB
    unsigned short* h   = (unsigned short*)wsp;  wsp += (size_t)N * 128 * 2;      // 12.8 MB
    unsigned char* p2   = (unsigned char*)wsp;   wsp += (size_t)(N + 1) * 64;     //  3.2 MB (1 slab)
    unsigned short* r2  = (unsigned short*)wsp;  wsp += (size_t)N * 64 * 2;       //  6.4 MB
    unsigned short* xb  = (unsigned short*)wsp;  wsp += (size_t)N * 128 * 2;      // 12.8 MB
    unsigned int* pairs = (unsigned int*)wsp;    wsp += (size_t)E * 4;            //  6.4 MB
    unsigned short* csr = (unsigned short*)wsp;  wsp += (size_t)NB * CSTRIDE * 2; //  4.8 MB
    unsigned short* Wb  = (unsigned short*)wsp;  wsp += (size_t)49152 * 2;
    unsigned int* counts= (unsigned int*)wsp;    wsp += (size_t)NBLK1 * 256 * 4;
    int* rowptr         = (int*)wsp;             wsp += (size_t)(N + 1) * 4;
    unsigned short* degs= (unsigned short*)wsp;  wsp += (size_t)((N + 1) & ~1) * 2;

    unsigned short* Wl1b = Wb;
    unsigned short* Wr1b = Wb + 16384;
    unsigned short* Wl2b = Wb + 32768;
    unsigned short* Wr2b = Wb + 40960;

    const int nx4 = N * 128 / 4;
    const int castBlocks = (nx4 + 49152 + THREADS - 1) / THREADS;
    const int MT = (N + 15) / 16;                 // 3125
    const int gemmBlocks = (MT + 3) / 4;          // 782
    const int NB32 = (N + 31) / 32;               // 1563 (32-node gather blocks)

    // D1: fused cast + CSR part1 + fp8 zero-row init
    fused_cast_p1<<<NBLK1 + castBlocks, THREADS, 0, stream>>>(
        x, Wl1, Wr1, Wl2, Wr2, xb, Wb, nx4, src, dstv, pairs, counts, E, chunk, NB,
        p1, p2, N);

    // D2: layer-1 GEMM (jobs 0,1 -> p1 fp8 slabs; 2,3 -> r1 bf16) + finalize
    gemm128_csr<<<dim3(gemmBlocks, 5), THREADS, 0, stream>>>(
        xb, Wl1b, Wr1b, b1, p1, r1, N,
        pairs, counts, rowptr, degs, csr, N, E, NB, chunk);

    // D3: gather layer 1 (2 fp8 slabs, XCD-quad pinned)
    gather_h<<<8 * ((NB32 + 3) / 4), GTH, 0, stream>>>(
        p1, rowptr, degs, csr, r1, h, N, NB32);

    // D4: layer-2 GEMM (job 0 -> p2 fp8; 1 -> r2 bf16)
    gemm64<<<dim3(gemmBlocks, 2), THREADS, 0, stream>>>(h, Wl2b, Wr2b, b2, p2, r2, N);

    // D5: gather layer 2 -> final output (1 fp8 slab)
    gather_out<<<NB32, GTH, 0, stream>>>(p2, rowptr, degs, csr, r2, out, N, NB32);
}

// Round 8
// 218.122 us; speedup vs baseline: 1.3878x; 1.0440x over previous
//
#include <hip/hip_runtime.h>
#include <hip/hip_bf16.h>

// GraphSAGE 2-layer forward.
// R22 = R21 + LUT finalize (binary-search removal):
//  - R21 post-mortem: fp8 halved the gather (out of top-5); the pole is now
//    gemm128_csr at 54us, which has been ~54us since R17 — the finalize's
//    9-step dependent-LDS binary search per element (x2 passes x1.6M
//    elements) is the critical path, not the GEMM (MfmaUtil 2% = 1.2us).
//  - Fix: materialize run membership ONCE into an LDS LUT (16 threads/run
//    write lut[runbase[blk]..)=blk), then both passes do a single
//    independent LDS read per element. LDS 7.7->31KB (still 5 blocks/CU).
//  - Everything else unchanged from R21 (fp8 p-tables, XCD pinning,
//    sentinel-padded csr, 32-node gather blocks).

#define THREADS 256
#define GTH 128            // gather block size (32 nodes x 4 lanes)
#define NBLK1 512          // csr part1 blocks (chunk = 3125 <= 3328 stage cap)
#define CSTRIDE 12288      // padded csr entries per 256-node bucket

typedef __bf16 bf16x8 __attribute__((ext_vector_type(8)));
typedef float floatx4 __attribute__((ext_vector_type(4)));
typedef float f32x4 __attribute__((ext_vector_type(4)));
typedef float f32x2 __attribute__((ext_vector_type(2)));
typedef unsigned int u32x4 __attribute__((ext_vector_type(4)));

union ABfrag { bf16x8 v; unsigned short u[8]; uint4 q; };
union V4 { u32x4 w; uint4 q; };

static __device__ __forceinline__ unsigned short f2bf(float f) {
    unsigned int u = __float_as_uint(f);
    u = (u + 0x7fffu + ((u >> 16) & 1u)) >> 16;   // RNE
    return (unsigned short)u;
}

static __device__ __forceinline__ unsigned char f2fp8(float f) {
    int pk = __builtin_amdgcn_cvt_pk_fp8_f32(f, f, 0, false);   // OCP e4m3, RNE+sat
    return (unsigned char)(pk & 0xff);
}

static __device__ __forceinline__ void unpack8(float* o, uint4 v) {
    o[0] = __uint_as_float(v.x << 16);
    o[1] = __uint_as_float(v.x & 0xffff0000u);
    o[2] = __uint_as_float(v.y << 16);
    o[3] = __uint_as_float(v.y & 0xffff0000u);
    o[4] = __uint_as_float(v.z << 16);
    o[5] = __uint_as_float(v.z & 0xffff0000u);
    o[6] = __uint_as_float(v.w << 16);
    o[7] = __uint_as_float(v.w & 0xffff0000u);
}

// decode 16 fp8 (one uint4 = 16 cols) and accumulate into acc[16]
static __device__ __forceinline__ void accf8(float* acc, uint4 v) {
    unsigned w[4] = {v.x, v.y, v.z, v.w};
    #pragma unroll
    for (int j = 0; j < 4; ++j) {
        f32x2 a = __builtin_amdgcn_cvt_pk_f32_fp8(w[j], false);
        f32x2 c = __builtin_amdgcn_cvt_pk_f32_fp8(w[j], true);
        acc[j * 4 + 0] += a[0];
        acc[j * 4 + 1] += a[1];
        acc[j * 4 + 2] += c[0];
        acc[j * 4 + 3] += c[1];
    }
}

// 8 fp8 row-gathers (one 64B line each), all loads issued before any decode.
static __device__ __forceinline__ void gath8f(float* acc, const unsigned char* __restrict__ ps,
                                              u32x4 c, int lane) {
    unsigned s[8];
    s[0] = c[0] & 0xffffu; s[1] = c[0] >> 16;
    s[2] = c[1] & 0xffffu; s[3] = c[1] >> 16;
    s[4] = c[2] & 0xffffu; s[5] = c[2] >> 16;
    s[6] = c[3] & 0xffffu; s[7] = c[3] >> 16;
    uint4 v[8];
    #pragma unroll
    for (int i = 0; i < 8; ++i)
        v[i] = *(const uint4*)(ps + (size_t)s[i] * 64 + lane * 16);
    #pragma unroll
    for (int i = 0; i < 8; ++i) accf8(acc, v[i]);
}

// 16 fp8 row-gathers in flight (2 csr vectors).
static __device__ __forceinline__ void gath16f(float* acc, const unsigned char* __restrict__ ps,
                                               u32x4 c0, u32x4 c1, int lane) {
    unsigned s[16];
    s[0] = c0[0] & 0xffffu;  s[1] = c0[0] >> 16;
    s[2] = c0[1] & 0xffffu;  s[3] = c0[1] >> 16;
    s[4] = c0[2] & 0xffffu;  s[5] = c0[2] >> 16;
    s[6] = c0[3] & 0xffffu;  s[7] = c0[3] >> 16;
    s[8] = c1[0] & 0xffffu;  s[9] = c1[0] >> 16;
    s[10] = c1[1] & 0xffffu; s[11] = c1[1] >> 16;
    s[12] = c1[2] & 0xffffu; s[13] = c1[2] >> 16;
    s[14] = c1[3] & 0xffffu; s[15] = c1[3] >> 16;
    uint4 v[16];
    #pragma unroll
    for (int i = 0; i < 16; ++i)
        v[i] = *(const uint4*)(ps + (size_t)s[i] * 64 + lane * 16);
    #pragma unroll
    for (int i = 0; i < 16; ++i) accf8(acc, v[i]);
}

// ---------------------------------------------------------------------------
// D1: fused cast (x->bf16, W->bf16) + CSR part1 + fp8 zero-row init.
__global__ __launch_bounds__(THREADS)
void fused_cast_p1(const float* __restrict__ x, const float* __restrict__ wa,
                   const float* __restrict__ wb, const float* __restrict__ wc,
                   const float* __restrict__ wd, unsigned short* __restrict__ xb,
                   unsigned short* __restrict__ Wb, int nx4,
                   const int* __restrict__ src, const int* __restrict__ dst,
                   unsigned int* __restrict__ pairs, unsigned int* __restrict__ counts,
                   int E, int chunk, int NB,
                   unsigned char* __restrict__ p1z, unsigned char* __restrict__ p2z, int Nn) {
    __shared__ int lh[THREADS], lsc[THREADS], lpos[THREADS];
    __shared__ unsigned int stage[3328];
    int t = threadIdx.x;
    if (blockIdx.x < NBLK1) {
        int e0 = blockIdx.x * chunk, e1 = min(E, e0 + chunk);
        lh[t] = 0;
        __syncthreads();
        for (int e = e0 + t; e < e1; e += THREADS) atomicAdd(&lh[dst[e] >> 8], 1);
        __syncthreads();
        int v = lh[t];
        lsc[t] = v;
        __syncthreads();
        for (int off = 1; off < THREADS; off <<= 1) {
            int tv = (t >= off) ? lsc[t - off] : 0;
            __syncthreads();
            lsc[t] += tv;
            __syncthreads();
        }
        int base = lsc[t] - v;
        lpos[t] = base;
        __syncthreads();
        for (int e = e0 + t; e < e1; e += THREADS) {
            int dd = dst[e];
            int p = atomicAdd(&lpos[dd >> 8], 1);
            stage[p] = (unsigned int)src[e] | ((unsigned int)(dd & 255) << 16);
        }
        __syncthreads();
        int n = e1 - e0;
        for (int i = t; i < n; i += THREADS) pairs[e0 + i] = stage[i];
        if (t < NB)
            counts[(size_t)blockIdx.x * 256 + t] = ((unsigned int)base << 16) | (unsigned int)v;
        return;
    }
    // fp8 zero-row init: p1 has 2 slabs stride (N+1)*64 B, p2 has 1
    if (blockIdx.x == NBLK1 && t < 192) {
        size_t Np64 = (size_t)(Nn + 1) * 64;
        if (t < 128) p1z[(size_t)(t >> 6) * Np64 + (size_t)Nn * 64 + (t & 63)] = 0;
        else         p2z[(size_t)Nn * 64 + (t - 128)] = 0;
    }
    int i = (blockIdx.x - NBLK1) * THREADS + t;
    if (i < nx4) {
        float4 v = ((const float4*)x)[i];
        ushort4 u;
        u.x = f2bf(v.x); u.y = f2bf(v.y); u.z = f2bf(v.z); u.w = f2bf(v.w);
        ((ushort4*)xb)[i] = u;
        return;
    }
    int j = i - nx4;
    if (j >= 49152) return;
    float v;
    if (j < 16384) v = wa[j];
    else if (j < 32768) v = wb[j - 16384];
    else if (j < 40960) v = wc[j - 32768];
    else v = wd[j - 40960];
    Wb[j] = f2bf(v);
}

// ---------------------------------------------------------------------------
// MFMA bf16 GEMM body. p-outputs (gathered later) are fp8 [slab][(M+1)][64]
// with zero row M; r-outputs stay bf16 slab-major [col>>5][M][32] (+bias).
template<int NOUT, bool ASLAB>
static __device__ __forceinline__
void gemm_body(const unsigned short* __restrict__ A, const unsigned short* __restrict__ W0,
               const unsigned short* __restrict__ W1, const float* __restrict__ biasR,
               unsigned char* __restrict__ pOut, unsigned short* __restrict__ rOut,
               int M, int job, int xt) {
    constexpr int CT = 4;
    int outSel, chalf;
    if (NOUT == 128) { outSel = job >> 1; chalf = job & 1; }
    else             { outSel = job;      chalf = 0; }
    const unsigned short* W = (outSel ? W1 : W0) + chalf * 64 * 128;

    const int wv = threadIdx.x >> 6, ln = threadIdx.x & 63;
    const int bl = ln & 15, quad = ln >> 4;
    const int mt = xt * 4 + wv;
    const size_t M32 = (size_t)M * 32;
    const size_t Mp64 = (size_t)(M + 1) * 64;

    ABfrag Bf[CT][4];
    #pragma unroll
    for (int ct = 0; ct < CT; ++ct)
        #pragma unroll
        for (int ks = 0; ks < 4; ++ks)
            Bf[ct][ks].q = *(const uint4*)&W[(size_t)(ct * 16 + bl) * 128 + ks * 32 + quad * 8];

    if (mt * 16 >= M) return;
    const int m0 = mt * 16;
    const int arow = m0 + bl;

    floatx4 acc[CT];
    #pragma unroll
    for (int ct = 0; ct < CT; ++ct) acc[ct] = (floatx4){0.f, 0.f, 0.f, 0.f};

    #pragma unroll
    for (int ks = 0; ks < 4; ++ks) {
        ABfrag Af;
        if (ASLAB) Af.q = *(const uint4*)&A[(size_t)ks * M32 + (size_t)arow * 32 + quad * 8];
        else       Af.q = *(const uint4*)&A[(size_t)arow * 128 + ks * 32 + quad * 8];
        #pragma unroll
        for (int ct = 0; ct < CT; ++ct)
            acc[ct] = __builtin_amdgcn_mfma_f32_16x16x32_bf16(Af.v, Bf[ct][ks].v, acc[ct], 0, 0, 0);
    }

    if (outSel) {
        // bf16 r-out with bias, slab-major 32-col
        #pragma unroll
        for (int ct = 0; ct < CT; ++ct) {
            int col = chalf * 64 + ct * 16 + bl;
            int slab = col >> 5, wi = col & 31;
            size_t sbase = (size_t)slab * M32;
            float bv = biasR[col];
            #pragma unroll
            for (int i = 0; i < 4; ++i) {
                int row = m0 + quad * 4 + i;
                rOut[sbase + (size_t)row * 32 + wi] = f2bf(acc[ct][i] + bv);
            }
        }
    } else {
        // fp8 p-out, [slab8][(M+1)][64], no bias
        #pragma unroll
        for (int ct = 0; ct < CT; ++ct) {
            int col = chalf * 64 + ct * 16 + bl;
            int slab8 = col >> 6, wi = col & 63;
            unsigned char* pp = pOut + (size_t)slab8 * Mp64;
            #pragma unroll
            for (int i = 0; i < 4; ++i) {
                int row = m0 + quad * 4 + i;
                pp[(size_t)row * 64 + wi] = f2fp8(acc[ct][i]);
            }
        }
    }
}

// ---------------------------------------------------------------------------
// D2: fused layer-1 GEMM + LUT-based CSR finalize.
// grid (gemmBlocks, 5): y>=1 -> gemm job y-1; y==0 && x<NB -> finalize.
__global__ __launch_bounds__(THREADS)
void gemm128_csr(const unsigned short* __restrict__ A, const unsigned short* __restrict__ W0,
                 const unsigned short* __restrict__ W1, const float* __restrict__ biasR,
                 unsigned char* __restrict__ pOut, unsigned short* __restrict__ rOut, int M,
                 const unsigned int* __restrict__ pairs, const unsigned int* __restrict__ counts,
                 int* __restrict__ rowptr, unsigned short* __restrict__ degs,
                 unsigned short* __restrict__ csr, int N, int E, int NB, int chunk) {
    __shared__ int runsrc[NBLK1];
    __shared__ int runbase[NBLK1 + 1];
    __shared__ unsigned short lut[CSTRIDE];          // element -> run id
    __shared__ int lhist[THREADS], lscan[THREADS], loff[THREADS];

    if (blockIdx.y != 0) {
        gemm_body<128, false>(A, W0, W1, biasR, pOut, rOut, M, blockIdx.y - 1, blockIdx.x);
        return;
    }
    int b = blockIdx.x, t = threadIdx.x;
    if (b >= NB) return;

    // per-run {length, source offset} from counts; scan lengths -> runbase
    unsigned int pc0 = counts[(size_t)t * 256 + b];
    unsigned int pc1 = counts[(size_t)(t + 256) * 256 + b];
    int c0 = (int)(pc0 & 0xffffu), c1 = (int)(pc1 & 0xffffu);
    runsrc[t] = t * chunk + (int)(pc0 >> 16);
    runsrc[t + 256] = (t + 256) * chunk + (int)(pc1 >> 16);
    lscan[t] = c0;
    __syncthreads();
    for (int off = 1; off < THREADS; off <<= 1) {
        int xx = (t >= off) ? lscan[t - off] : 0;
        __syncthreads();
        lscan[t] += xx;
        __syncthreads();
    }
    runbase[t] = lscan[t] - c0;
    int S0 = lscan[THREADS - 1];
    __syncthreads();
    lscan[t] = c1;
    __syncthreads();
    for (int off = 1; off < THREADS; off <<= 1) {
        int xx = (t >= off) ? lscan[t - off] : 0;
        __syncthreads();
        lscan[t] += xx;
        __syncthreads();
    }
    runbase[256 + t] = S0 + lscan[t] - c1;
    if (t == THREADS - 1) runbase[512] = S0 + lscan[t];
    lhist[t] = 0;
    __syncthreads();
    int sz = runbase[512];

    // LUT fill: 16 threads per run write its id over [runbase, runbase+len)
    int rid = t >> 4, j0 = t & 15;
    for (int blk = rid; blk < NBLK1; blk += 16) {
        int d0 = runbase[blk];
        int len = runbase[blk + 1] - d0;
        for (int j = j0; j < len; j += 16) lut[d0 + j] = (unsigned short)blk;
    }
    __syncthreads();

    // Pass A: flat-index histogram. Per element: one independent LDS LUT
    // read + one coalesced pairs load + one LDS atomic (x4 unroll for MLP).
    for (int i0 = t; i0 < sz; i0 += 4 * THREADS) {
        unsigned pv[4];
        int ok[4];
        #pragma unroll
        for (int k = 0; k < 4; ++k) {
            int i = i0 + k * THREADS;
            ok[k] = (i < sz);
            int idx = ok[k] ? i : (sz - 1);
            int run = lut[idx];
            pv[k] = pairs[runsrc[run] + (idx - runbase[run])];
        }
        #pragma unroll
        for (int k = 0; k < 4; ++k)
            if (ok[k]) atomicAdd(&lhist[(pv[k] >> 16) & 255], 1);
    }
    __syncthreads();

    // padded (8-aligned) counts -> scan -> rowptr / degs / loff / sentinel pads
    int v = lhist[t];
    int pcv = (v + 7) & ~7;
    lscan[t] = pcv;
    __syncthreads();
    for (int off = 1; off < THREADS; off <<= 1) {
        int xx = (t >= off) ? lscan[t - off] : 0;
        __syncthreads();
        lscan[t] += xx;
        __syncthreads();
    }
    int rel = lscan[t] - pcv;
    int base = b * CSTRIDE + rel;
    int id = (b << 8) + t;
    if (id < N) {
        rowptr[id] = base;
        degs[id] = (unsigned short)v;
    }
    loff[t] = base;
    for (int i = v; i < pcv; ++i) csr[base + i] = (unsigned short)N;  // sentinel -> zero row
    __syncthreads();

    // Pass B: flat-index scatter (pairs L2-warm from pass A).
    for (int i0 = t; i0 < sz; i0 += 4 * THREADS) {
        unsigned pv[4];
        int ok[4];
        #pragma unroll
        for (int k = 0; k < 4; ++k) {
            int i = i0 + k * THREADS;
            ok[k] = (i < sz);
            int idx = ok[k] ? i : (sz - 1);
            int run = lut[idx];
            pv[k] = pairs[runsrc[run] + (idx - runbase[run])];
        }
        #pragma unroll
        for (int k = 0; k < 4; ++k)
            if (ok[k]) {
                int pos = atomicAdd(&loff[(pv[k] >> 16) & 255], 1);
                csr[pos] = (unsigned short)(pv[k] & 0xffffu);
            }
    }
}

// D4: layer-2 GEMM (A = h bf16 slab-major; p2 fp8, r2 bf16).
__global__ __launch_bounds__(THREADS)
void gemm64(const unsigned short* __restrict__ A, const unsigned short* __restrict__ W0,
            const unsigned short* __restrict__ W1, const float* __restrict__ b2,
            unsigned char* __restrict__ p2, unsigned short* __restrict__ r2, int M) {
    gemm_body<64, true>(A, W0, W1, b2, p2, r2, M, blockIdx.y, blockIdx.x);
}

// ---------------------------------------------------------------------------
// D3: gather layer 1 (fp8). 32-node blocks of 128 threads; 4 lanes/node;
// p1 = 2 fp8 slabs of 64 cols (one 64B line per row-gather), pinned to XCD
// quads. h out / r1 in stay bf16 [4][N][32].
__global__ __launch_bounds__(GTH)
void gather_h(const unsigned char* __restrict__ p1, const int* __restrict__ rowptr,
              const unsigned short* __restrict__ degs, const unsigned short* __restrict__ csr,
              const unsigned short* __restrict__ r1, unsigned short* __restrict__ h,
              int N, int nodeBlocks) {
    __shared__ int sdeg[32], perm[32];
    const size_t N32 = (size_t)N * 32;
    const size_t Np64 = (size_t)(N + 1) * 64;
    int b = blockIdx.x;
    int slab = (b & 7) >> 2;                    // 2 slabs, one XCD quad each
    int nb = ((b >> 3) << 2) | (b & 3);
    if (nb >= nodeBlocks) return;
    int g0 = nb * 32;
    int t = threadIdx.x;
    if (t < 32) {
        int g = g0 + t;
        sdeg[t] = (g < N) ? (int)degs[g] : -1;
    }
    __syncthreads();
    if (t < 32) {
        int d = sdeg[t], r = 0;
        #pragma unroll 8
        for (int j = 0; j < 32; ++j) {
            int dj = sdeg[j];
            r += (dj < d) || (dj == d && j < t);
        }
        perm[r] = t;
    }
    __syncthreads();
    int g = g0 + perm[t >> 2];
    if (g >= N) return;
    int lane = t & 3;
    const unsigned char* ps = p1 + (size_t)slab * Np64;
    int start = rowptr[g];
    int deg = degs[g];
    int niter = (deg + 7) >> 3;
    // bf16 self-term: global col = slab*64 + lane*16 + i
    int ks = slab * 2 + (lane >> 1);
    int co = (lane & 1) * 16;
    const unsigned short* rp = r1 + (size_t)ks * N32 + (size_t)g * 32 + co;
    V4 rv0, rv1;
    rv0.w = __builtin_nontemporal_load((const u32x4*)rp);
    rv1.w = __builtin_nontemporal_load((const u32x4*)(rp + 8));
    float acc[16];
    #pragma unroll
    for (int i = 0; i < 16; ++i) acc[i] = 0.f;
    const unsigned short* cp = csr + start;   // 16B aligned by construction
    int nit2 = niter & ~1;
    int it = 0;
    for (; it < nit2; it += 2) {
        u32x4 c0 = __builtin_nontemporal_load((const u32x4*)(cp + it * 8));
        u32x4 c1 = __builtin_nontemporal_load((const u32x4*)(cp + it * 8 + 8));
        gath16f(acc, ps, c0, c1, lane);
    }
    if (it < niter) {
        u32x4 c = __builtin_nontemporal_load((const u32x4*)(cp + it * 8));
        gath8f(acc, ps, c, lane);
    }
    float rc = 1.0f / fmaxf((float)deg, 1.0f);
    float rr[16];
    unpack8(rr, rv0.q);
    unpack8(rr + 8, rv1.q);
    float o[16];
    #pragma unroll
    for (int i = 0; i < 16; ++i) o[i] = fmaxf(acc[i] * rc + rr[i], 0.f);
    u32x4 u0, u1;
    #pragma unroll
    for (int k = 0; k < 4; ++k) {
        u0[k] = (unsigned)f2bf(o[2 * k]) | ((unsigned)f2bf(o[2 * k + 1]) << 16);
        u1[k] = (unsigned)f2bf(o[8 + 2 * k]) | ((unsigned)f2bf(o[8 + 2 * k + 1]) << 16);
    }
    unsigned short* hp = h + (size_t)ks * N32 + (size_t)g * 32 + co;
    __builtin_nontemporal_store(u0, (u32x4*)hp);
    __builtin_nontemporal_store(u1, (u32x4*)(hp + 8));
}

// D5: gather layer 2 (fp8, final). p2 = 1 fp8 slab of 64 cols; r2 bf16
// [2][N][32]; out f32 [N][64].
__global__ __launch_bounds__(GTH)
void gather_out(const unsigned char* __restrict__ p2, const int* __restrict__ rowptr,
                const unsigned short* __restrict__ degs, const unsigned short* __restrict__ csr,
                const unsigned short* __restrict__ r2, float* __restrict__ out,
                int N, int nodeBlocks) {
    __shared__ int sdeg[32], perm[32];
    const size_t N32 = (size_t)N * 32;
    int b = blockIdx.x;
    if (b >= nodeBlocks) return;
    int g0 = b * 32;
    int t = threadIdx.x;
    if (t < 32) {
        int g = g0 + t;
        sdeg[t] = (g < N) ? (int)degs[g] : -1;
    }
    __syncthreads();
    if (t < 32) {
        int d = sdeg[t], r = 0;
        #pragma unroll 8
        for (int j = 0; j < 32; ++j) {
            int dj = sdeg[j];
            r += (dj < d) || (dj == d && j < t);
        }
        perm[r] = t;
    }
    __syncthreads();
    int g = g0 + perm[t >> 2];
    if (g >= N) return;
    int lane = t & 3;
    int start = rowptr[g];
    int deg = degs[g];
    int niter = (deg + 7) >> 3;
    int ks = lane >> 1;
    int co = (lane & 1) * 16;
    const unsigned short* rp = r2 + (size_t)ks * N32 + (size_t)g * 32 + co;
    V4 rv0, rv1;
    rv0.w = __builtin_nontemporal_load((const u32x4*)rp);
    rv1.w = __builtin_nontemporal_load((const u32x4*)(rp + 8));
    float acc[16];
    #pragma unroll
    for (int i = 0; i < 16; ++i) acc[i] = 0.f;
    const unsigned short* cp = csr + start;
    int nit2 = niter & ~1;
    int it = 0;
    for (; it < nit2; it += 2) {
        u32x4 c0 = __builtin_nontemporal_load((const u32x4*)(cp + it * 8));
        u32x4 c1 = __builtin_nontemporal_load((const u32x4*)(cp + it * 8 + 8));
        gath16f(acc, p2, c0, c1, lane);
    }
    if (it < niter) {
        u32x4 c = __builtin_nontemporal_load((const u32x4*)(cp + it * 8));
        gath8f(acc, p2, c, lane);
    }
    float rc = 1.0f / fmaxf((float)deg, 1.0f);
    float rr[16];
    unpack8(rr, rv0.q);
    unpack8(rr + 8, rv1.q);
    float* op = out + (size_t)g * 64 + lane * 16;
    #pragma unroll
    for (int q = 0; q < 4; ++q) {
        f32x4 o;
        #pragma unroll
        for (int k = 0; k < 4; ++k) o[k] = acc[q * 4 + k] * rc + rr[q * 4 + k];
        __builtin_nontemporal_store(o, (f32x4*)(op + q * 4));
    }
}

// ---------------------------------------------------------------------------
extern "C" void kernel_launch(void* const* d_in, const int* in_sizes, int n_in,
                              void* d_out, int out_size, void* d_ws, size_t ws_size,
                              hipStream_t stream) {
    const float* x   = (const float*)d_in[0];
    const int* edges = (const int*)d_in[1];
    const float* Wl1 = (const float*)d_in[2];
    const float* Wr1 = (const float*)d_in[3];
    const float* b1  = (const float*)d_in[4];
    const float* Wl2 = (const float*)d_in[5];
    const float* Wr2 = (const float*)d_in[6];
    const float* b2  = (const float*)d_in[7];
    float* out = (float*)d_out;

    const int N = in_sizes[0] / 128;     // 50000 (< 65536)
    const int E = in_sizes[1] / 2;       // 1600000
    const int NB = (N + 255) >> 8;       // 196
    const int chunk = (E + NBLK1 - 1) / NBLK1;   // 3125
    const int* src = edges;
    const int* dstv = edges + E;

    // Workspace: fp8 p-tables (zero row N), bf16 r/h tables
    char* wsp = (char*)d_ws;
    unsigned char* p1   = (unsigned char*)wsp;   wsp += (size_t)(N + 1) * 128;    //  6.4 MB (2 slabs x 64B)
    unsigned short* r1  = (unsigned short*)wsp;  wsp += (size_t)N * 128 * 2;      // 12.8 MB
    unsigned short* h   = (unsigned short*)wsp;  wsp += (size_t)N * 128 * 2;      // 12.8 MB
    unsigned char* p2   = (unsigned char*)wsp;   wsp += (size_t)(N + 1) * 64;     //  3.2 MB (1 slab)
    unsigned short* r2  = (unsigned short*)wsp;  wsp += (size_t)N * 64 * 2;       //  6.4 MB
    unsigned short* xb  = (unsigned short*)wsp;  wsp += (size_t)N * 128 * 2;      // 12.8 MB
    unsigned int* pairs = (unsigned int*)wsp;    wsp += (size_t)E * 4;            //  6.4 MB
    unsigned short* csr = (unsigned short*)wsp;  wsp += (size_t)NB * CSTRIDE * 2; //  4.8 MB
    unsigned short* Wb  = (unsigned short*)wsp;  wsp += (size_t)49152 * 2;
    unsigned int* counts= (unsigned int*)wsp;    wsp += (size_t)NBLK1 * 256 * 4;
    int* rowptr         = (int*)wsp;             wsp += (size_t)(N + 1) * 4;
    unsigned short* degs= (unsigned short*)wsp;  wsp += (size_t)((N + 1) & ~1) * 2;

    unsigned short* Wl1b = Wb;
    unsigned short* Wr1b = Wb + 16384;
    unsigned short* Wl2b = Wb + 32768;
    unsigned short* Wr2b = Wb + 40960;

    const int nx4 = N * 128 / 4;
    const int castBlocks = (nx4 + 49152 + THREADS - 1) / THREADS;
    const int MT = (N + 15) / 16;                 // 3125
    const int gemmBlocks = (MT + 3) / 4;          // 782
    const int NB32 = (N + 31) / 32;               // 1563 (32-node gather blocks)

    // D1: fused cast + CSR part1 + fp8 zero-row init
    fused_cast_p1<<<NBLK1 + castBlocks, THREADS, 0, stream>>>(
        x, Wl1, Wr1, Wl2, Wr2, xb, Wb, nx4, src, dstv, pairs, counts, E, chunk, NB,
        p1, p2, N);

    // D2: layer-1 GEMM (jobs 0,1 -> p1 fp8 slabs; 2,3 -> r1 bf16) + finalize
    gemm128_csr<<<dim3(gemmBlocks, 5), THREADS, 0, stream>>>(
        xb, Wl1b, Wr1b, b1, p1, r1, N,
        pairs, counts, rowptr, degs, csr, N, E, NB, chunk);

    // D3: gather layer 1 (2 fp8 slabs, XCD-quad pinned)
    gather_h<<<8 * ((NB32 + 3) / 4), GTH, 0, stream>>>(
        p1, rowptr, degs, csr, r1, h, N, NB32);

    // D4: layer-2 GEMM (job 0 -> p2 fp8; 1 -> r2 bf16)
    gemm64<<<dim3(gemmBlocks, 2), THREADS, 0, stream>>>(h, Wl2b, Wr2b, b2, p2, r2, N);

    // D5: gather layer 2 -> final output (1 fp8 slab)
    gather_out<<<NB32, GTH, 0, stream>>>(p2, rowptr, degs, csr, r2, out, N, NB32);
}